// Round 7
// baseline (138.420 us; speedup 1.0000x reference)
//
#include <hip/hip_runtime.h>

// ---------------------------------------------------------------------------
// MoE gated MLP with LoRA, top-2 of 8, T=512, H=2048, I=1024, R=16.
// Round 7: finer ct (B still read once), XCD-grouped block ids for A/h L2
// residency, float4-vectorized B staging. K-loop/pipeline from round 6.
// ---------------------------------------------------------------------------

typedef short  s16x8 __attribute__((ext_vector_type(8)));
typedef float  f32x4 __attribute__((ext_vector_type(4)));
typedef unsigned short u16x4 __attribute__((ext_vector_type(4)));
typedef unsigned short u16x8 __attribute__((ext_vector_type(8)));

__device__ __forceinline__ unsigned short f2bf(float f) {
  unsigned u = __builtin_bit_cast(unsigned, f);
  u += 0x7fffu + ((u >> 16) & 1u);          // RNE
  return (unsigned short)(u >> 16);
}

// Barrier that does NOT drain vmcnt.
#define PIPE_BARRIER() asm volatile("s_waitcnt lgkmcnt(0)\n\ts_barrier" ::: "memory")

// ---- workspace layout (bytes). [0, ZERO_SPAN) memset to 0 each launch ----
#define OFF_CNT    0u          // 8 int (pad 256)
#define OFF_TER1A  256u        // 512*128 f32 = 262144
#define OFF_TER2   262400u     // 1024*16 f32 = 65536
#define ZERO_SPAN  327936u
#define OFF_LIST   327936u     // 8*512 int = 16384
#define OFF_PW     344320u     // 1024 f32 = 4096
#define OFF_WG     348416u     // 8*2048 f32 = 65536
#define OFF_XBF    413952u     // 512*2048 bf16 = 2097152
#define OFF_H      2511104u    // 1024*1024 bf16 = 2097152
#define OFF_OSEL   4608256u    // 1024*2048 f32 = 8388608
// total ~13.0 MB

// ---------------------------------------------------------------------------
__global__ void k_gatecomb(const float* __restrict__ gw, const float* __restrict__ gA,
                           const float* __restrict__ gB, float* __restrict__ Wg) {
  int idx = blockIdx.x * 256 + threadIdx.x;   // 16384
  int e = idx >> 11, h = idx & 2047;
  float acc = gw[idx];
#pragma unroll
  for (int r = 0; r < 16; ++r)
    acc += 2.0f * gB[e * 16 + r] * gA[r * 2048 + h];
  Wg[idx] = acc;
}

// fp32 router (exact logits -> identical top-k to reference) + fused x->bf16.
__global__ void k_router(const float* __restrict__ x, const float* __restrict__ Wg,
                         int* __restrict__ cnt, int* __restrict__ list,
                         float* __restrict__ pw, unsigned short* __restrict__ xbf) {
  int t = blockIdx.x, tid = threadIdx.x;
  __shared__ float xs[2048];
  __shared__ float logits[8];
  for (int i = tid; i < 2048; i += 256) xs[i] = x[(size_t)t * 2048 + i];
  __syncthreads();
  {
    u16x8 o;
#pragma unroll
    for (int j = 0; j < 8; ++j) o[j] = f2bf(xs[tid * 8 + j]);
    *(u16x8*)(xbf + (size_t)t * 2048 + tid * 8) = o;
  }
  int e = tid >> 5, l = tid & 31;
  float s = 0.f;
  for (int h = l; h < 2048; h += 32) s += xs[h] * Wg[e * 2048 + h];
#pragma unroll
  for (int off = 16; off >= 1; off >>= 1) s += __shfl_down(s, off, 32);
  if (l == 0) logits[e] = s;
  __syncthreads();
  if (tid == 0) {
    float m = logits[0];
#pragma unroll
    for (int i = 1; i < 8; ++i) m = fmaxf(m, logits[i]);
    float ex[8];
#pragma unroll
    for (int i = 0; i < 8; ++i) ex[i] = __expf(logits[i] - m);
    int e1 = 0; float v1 = ex[0];
#pragma unroll
    for (int i = 1; i < 8; ++i) if (ex[i] > v1) { v1 = ex[i]; e1 = i; }
    int e2 = -1; float v2 = -1.f;
#pragma unroll
    for (int i = 0; i < 8; ++i) if (i != e1 && ex[i] > v2) { v2 = ex[i]; e2 = i; }
    float inv = 1.f / (v1 + v2);
    int p1 = 2 * t, p2 = 2 * t + 1;
    pw[p1] = v1 * inv;
    pw[p2] = v2 * inv;
    int s1 = atomicAdd(&cnt[e1], 1); list[e1 * 512 + s1] = p1;
    int s2 = atomicAdd(&cnt[e2], 1); list[e2 * 512 + s2] = p2;
  }
}

// ter1all[t][er] = x[t] . gupA_flat[er]  (er = e*16+r). Round-2-proven.
__global__ __launch_bounds__(512) void k_ter1all(
    const unsigned short* __restrict__ xbf, const float* __restrict__ gupA,
    float* __restrict__ ter1all) {
  int trow = blockIdx.x, kcc = blockIdx.y;
  int tid = threadIdx.x;
  __shared__ unsigned short Ap[2][64 * 64];
  __shared__ unsigned short Bp[2][128 * 64];
  const int k0b = kcc * 512;

  int rowA = tid >> 3, k16A = tid & 7;
  const unsigned short* aSrc = xbf + (size_t)(trow * 64 + rowA) * 2048 + k0b + k16A * 8;
  int aOff = rowA * 64 + ((k16A * 8) ^ ((rowA & 7) << 3));

  const float* bSrc[2]; int bOff[2];
#pragma unroll
  for (int s = 0; s < 2; ++s) {
    int slot = tid + s * 512;
    int er = slot >> 3, kg = slot & 7;
    bSrc[s] = gupA + (size_t)er * 2048 + k0b + kg * 8;
    bOff[s] = er * 64 + ((kg * 8) ^ ((er & 7) << 3));
  }
  int lane = tid & 63, wv = tid >> 6;
  int lr = lane & 15, lh = lane >> 4;

  uint4 apre; float4 bpre[2][2];
#define TA_ISSUE(T) { int kk = (T) * 64;                                   \
    apre = *(const uint4*)(aSrc + kk);                                     \
    _Pragma("unroll") for (int s = 0; s < 2; ++s) {                        \
      bpre[s][0] = *(const float4*)(bSrc[s] + kk);                         \
      bpre[s][1] = *(const float4*)(bSrc[s] + kk + 4); } }

  f32x4 acc[4] = {};
  TA_ISSUE(0);
  for (int t = 0; t < 8; ++t) {
    int buf = t & 1;
    *(uint4*)&Ap[buf][aOff] = apre;
#pragma unroll
    for (int s = 0; s < 2; ++s) {
      u16x8 o;
      o[0]=f2bf(bpre[s][0].x); o[1]=f2bf(bpre[s][0].y); o[2]=f2bf(bpre[s][0].z); o[3]=f2bf(bpre[s][0].w);
      o[4]=f2bf(bpre[s][1].x); o[5]=f2bf(bpre[s][1].y); o[6]=f2bf(bpre[s][1].z); o[7]=f2bf(bpre[s][1].w);
      *(u16x8*)&Bp[buf][bOff[s]] = o;
    }
    __syncthreads();
    if (t < 7) TA_ISSUE(t + 1);
#pragma unroll
    for (int ks = 0; ks < 64; ks += 32) {
      int kb = ks + lh * 8;
      int bc = wv * 16 + lr;
      s16x8 b = *(const s16x8*)&Bp[buf][bc * 64 + (kb ^ ((bc & 7) << 3))];
#pragma unroll
      for (int fr = 0; fr < 4; ++fr) {
        int ar = fr * 16 + lr;
        s16x8 a = *(const s16x8*)&Ap[buf][ar * 64 + (kb ^ ((ar & 7) << 3))];
        acc[fr] = __builtin_amdgcn_mfma_f32_16x16x32_bf16(a, b, acc[fr], 0, 0, 0);
      }
    }
    __syncthreads();
  }
#undef TA_ISSUE
#pragma unroll
  for (int fr = 0; fr < 4; ++fr)
#pragma unroll
    for (int j = 0; j < 4; ++j) {
      int tok = trow * 64 + fr * 16 + lh * 4 + j;
      atomicAdd(&ter1all[tok * 128 + wv * 16 + lr], acc[fr][j]);
    }
}

// ---------------------------------------------------------------------------
// GEMM1: gathered x rows [BM=128] x gup[e], B-tile = 32 gate + 32 up cols,
// full K=2048 (NT=32). id = e + 8*(ct + 32*st): expert e -> XCD e so the
// shared A-panel stays L2-resident across its 32 ct-blocks.
// 8 waves = 4M x 2N; per wave 32 rows x 16 i-cols (g and u).
__global__ __launch_bounds__(512) void k_gemm1(
    const unsigned short* __restrict__ xbf, const float* __restrict__ gup,
    const float* __restrict__ gupB, const float* __restrict__ ter1all,
    const int* __restrict__ cnt, const int* __restrict__ list,
    unsigned short* __restrict__ h) {
  const int id = blockIdx.x;                 // 0..1023
  const int e  = id & 7;
  const int m  = id >> 3;
  const int ct = m & 31;                     // 0..31 : i-cols [ct*32, ct*32+32)
  const int st = m >> 5;                     // 0..3
  const int n = cnt[e];
  if (st * 128 >= n) return;
  const int tid = threadIdx.x;

  __shared__ unsigned short Ap[2][128 * 64];   // [row][k] swizzled
  __shared__ unsigned short Bp[2][64 * 64];    // [col][k]: 0..31 gate, 32..63 up

  const int c0 = ct * 32;

  const unsigned short *aSrc0, *aSrc1;
  int aOff0, aOff1;
  {
    int row = tid >> 3, k16 = tid & 7;
    int p = list[e * 512 + min(st * 128 + row, n - 1)];
    aSrc0 = xbf + (size_t)(p >> 1) * 2048 + k16 * 8;
    aOff0 = row * 64 + ((k16 * 8) ^ ((row & 7) << 3));
    int slot = tid + 512;
    row = slot >> 3; k16 = slot & 7;
    p = list[e * 512 + min(st * 128 + row, n - 1)];
    aSrc1 = xbf + (size_t)(p >> 1) * 2048 + k16 * 8;
    aOff1 = row * 64 + ((k16 * 8) ^ ((row & 7) << 3));
  }
  // B: thread owns 4 consecutive cols (c4..c4+3) x 2 k-rows (kr2, kr2+1)
  const int c4 = (tid & 15) * 4;             // 0..60
  const int kr2 = (tid >> 4) * 2;            // 0..62
  const int gcol = (c4 < 32) ? (c0 + c4) : (1024 + c0 + c4 - 32);
  const float* bSrc = gup + (size_t)e * 2048 * 2048 + (size_t)kr2 * 2048 + gcol;
  int bOffc[4];
#pragma unroll
  for (int cc = 0; cc < 4; ++cc)
    bOffc[cc] = (c4 + cc) * 64 + (kr2 ^ (((c4 + cc) & 7) << 3));

  const int lane = tid & 63, wv = tid >> 6;
  const int lr = lane & 15, lh = lane >> 4;
  const int wr = wv >> 1, ni = wv & 1;

  uint4 a0A, a1A, a0B, a1B;
  float bA[2][4], bB[2][4];

#define G1_LOAD(SUF, T) {                                          \
    const int kk = (T) * 64;                                       \
    a0##SUF = *(const uint4*)(aSrc0 + kk);                         \
    a1##SUF = *(const uint4*)(aSrc1 + kk);                         \
    *(float4*)&b##SUF[0][0] = *(const float4*)(bSrc + (size_t)kk * 2048);        \
    *(float4*)&b##SUF[1][0] = *(const float4*)(bSrc + (size_t)(kk + 1) * 2048); }

#define G1_BODY(BUF, SUF, NXT) {                                               \
    *(uint4*)&Ap[BUF][aOff0] = a0##SUF;                                        \
    *(uint4*)&Ap[BUF][aOff1] = a1##SUF;                                        \
    _Pragma("unroll") for (int cc = 0; cc < 4; ++cc) {                         \
      unsigned o = (unsigned)f2bf(b##SUF[0][cc]) |                             \
                   ((unsigned)f2bf(b##SUF[1][cc]) << 16);                      \
      *(unsigned*)&Bp[BUF][bOffc[cc]] = o;                                     \
    }                                                                          \
    PIPE_BARRIER();                                                            \
    if ((NXT) < 32) G1_LOAD(SUF, NXT);                                         \
    _Pragma("unroll") for (int ks = 0; ks < 64; ks += 32) {                    \
      int kb = ks + lh * 8;                                                    \
      s16x8 af[2], bg, bu;                                                     \
      _Pragma("unroll") for (int q = 0; q < 2; ++q) {                          \
        int ar = wr * 32 + q * 16 + lr;                                        \
        af[q] = *(const s16x8*)&Ap[BUF][ar * 64 + (kb ^ ((ar & 7) << 3))];     \
      }                                                                        \
      { int bc = ni * 16 + lr;                                                 \
        bg = *(const s16x8*)&Bp[BUF][bc * 64 + (kb ^ ((bc & 7) << 3))];        \
        bu = *(const s16x8*)&Bp[BUF][(bc + 32) * 64 + (kb ^ (((bc + 32) & 7) << 3))]; } \
      _Pragma("unroll") for (int q = 0; q < 2; ++q) {                          \
        accg[q] = __builtin_amdgcn_mfma_f32_16x16x32_bf16(af[q], bg, accg[q], 0, 0, 0); \
        accu[q] = __builtin_amdgcn_mfma_f32_16x16x32_bf16(af[q], bu, accu[q], 0, 0, 0); \
      }                                                                        \
    } }

  f32x4 accg[2] = {}, accu[2] = {};
  G1_LOAD(A, 0);
  G1_LOAD(B, 1);
  for (int tt = 0; tt < 32; tt += 2) {
    G1_BODY(0, A, tt + 2);
    G1_BODY(1, B, tt + 3);
  }
#undef G1_LOAD
#undef G1_BODY

  // ---- epilogue: stage ter1 rows to LDS, fuse LoRA + silu, store bf16 h ----
  __syncthreads();
  float* tlds = (float*)&Ap[0][0];             // 128 x 16 f32
  for (int idx = tid; idx < 2048; idx += 512) {
    int row = idx >> 4, c = idx & 15;
    int p = list[e * 512 + min(st * 128 + row, n - 1)];
    tlds[idx] = ter1all[(size_t)(p >> 1) * 128 + e * 16 + c];
  }
  __syncthreads();
  {
    int gc = c0 + ni * 16 + lr;                // global i-col 0..1023
    const float4* g4 = (const float4*)(gupB + ((size_t)e * 2048 + gc) * 16);
    const float4* u4 = (const float4*)(gupB + ((size_t)e * 2048 + 1024 + gc) * 16);
    float gv2[16], uv2[16];
#pragma unroll
    for (int q = 0; q < 4; ++q) {
      float4 gv = g4[q], uv = u4[q];
      gv2[q*4+0]=gv.x; gv2[q*4+1]=gv.y; gv2[q*4+2]=gv.z; gv2[q*4+3]=gv.w;
      uv2[q*4+0]=uv.x; uv2[q*4+1]=uv.y; uv2[q*4+2]=uv.z; uv2[q*4+3]=uv.w;
    }
#pragma unroll
    for (int q = 0; q < 2; ++q) {
#pragma unroll
      for (int j = 0; j < 4; ++j) {
        int row = wr * 32 + q * 16 + lh * 4 + j;
        if (st * 128 + row < n) {
          int p = list[e * 512 + st * 128 + row];
          const float* tv = &tlds[row * 16];
          float dg = 0.f, du = 0.f;
#pragma unroll
          for (int rr = 0; rr < 16; ++rr) { dg += tv[rr] * gv2[rr]; du += tv[rr] * uv2[rr]; }
          float g = accg[q][j] + 2.f * dg;
          float u = accu[q][j] + 2.f * du;
          h[(size_t)p * 1024 + gc] = f2bf(g / (1.f + __expf(-g)) * u);
        }
      }
    }
  }
}

// ter2[p][r] = h[p] . dlA[e][r], grouped MFMA GEMM (BN=16), split-K=4.
__global__ __launch_bounds__(512) void k_ter2(
    const unsigned short* __restrict__ h, const float* __restrict__ dlA,
    const int* __restrict__ cnt, const int* __restrict__ list,
    float* __restrict__ ter2) {
  int st = blockIdx.x, kcc = blockIdx.y, e = blockIdx.z;
  int n = cnt[e];
  if (st * 128 >= n) return;
  int tid = threadIdx.x;
  __shared__ unsigned short Ap[2][128 * 64];
  __shared__ unsigned short Bp[2][16 * 64];
  const int k0b = kcc * 256;

  const unsigned short* aSrc[2]; int aOff[2];
#pragma unroll
  for (int s = 0; s < 2; ++s) {
    int slot = tid + s * 512;
    int row = slot >> 3, k16 = slot & 7;
    int p = list[e * 512 + min(st * 128 + row, n - 1)];
    aSrc[s] = h + (size_t)p * 1024 + k0b + k16 * 8;
    aOff[s] = row * 64 + ((k16 * 8) ^ ((row & 7) << 3));
  }
  const float* bSrc = nullptr; int bOff = 0;
  if (tid < 128) {
    int r = tid >> 3, kg = tid & 7;
    bSrc = dlA + ((size_t)e * 16 + r) * 1024 + k0b + kg * 8;
    bOff = r * 64 + ((kg * 8) ^ ((r & 7) << 3));
  }
  int lane = tid & 63, wv = tid >> 6;
  int lr = lane & 15, lh = lane >> 4;

  uint4 apre[2]; float4 bpre[2];
#define T2_ISSUE(T) { int kk = (T) * 64;                                   \
    _Pragma("unroll") for (int s = 0; s < 2; ++s)                          \
        apre[s] = *(const uint4*)(aSrc[s] + kk);                           \
    if (tid < 128) { bpre[0] = *(const float4*)(bSrc + kk);                \
                     bpre[1] = *(const float4*)(bSrc + kk + 4); } }

  f32x4 acc = {};
  T2_ISSUE(0);
  for (int t = 0; t < 4; ++t) {
    int buf = t & 1;
#pragma unroll
    for (int s = 0; s < 2; ++s) *(uint4*)&Ap[buf][aOff[s]] = apre[s];
    if (tid < 128) {
      u16x8 o;
      o[0]=f2bf(bpre[0].x); o[1]=f2bf(bpre[0].y); o[2]=f2bf(bpre[0].z); o[3]=f2bf(bpre[0].w);
      o[4]=f2bf(bpre[1].x); o[5]=f2bf(bpre[1].y); o[6]=f2bf(bpre[1].z); o[7]=f2bf(bpre[1].w);
      *(u16x8*)&Bp[buf][bOff] = o;
    }
    __syncthreads();
    if (t < 3) T2_ISSUE(t + 1);
#pragma unroll
    for (int ks = 0; ks < 64; ks += 32) {
      int kb = ks + lh * 8;
      s16x8 b = *(const s16x8*)&Bp[buf][lr * 64 + (kb ^ ((lr & 7) << 3))];
      int ar = wv * 16 + lr;
      s16x8 a = *(const s16x8*)&Ap[buf][ar * 64 + (kb ^ ((ar & 7) << 3))];
      acc = __builtin_amdgcn_mfma_f32_16x16x32_bf16(a, b, acc, 0, 0, 0);
    }
    __syncthreads();
  }
#undef T2_ISSUE
#pragma unroll
  for (int j = 0; j < 4; ++j) {
    int row = wv * 16 + lh * 4 + j;
    if (st * 128 + row < n) {
      int p = list[e * 512 + st * 128 + row];
      atomicAdd(&ter2[p * 16 + lr], acc[j]);
    }
  }
}

// GEMM2: gathered h rows [BM=128] x down[e] [BN=32], full K=1024 (NT=16).
// id = e + 8*(ct + 64*st). Epilogue fuses down-LoRA, stores per-slot osel.
__global__ __launch_bounds__(512) void k_gemm2(
    const unsigned short* __restrict__ h, const float* __restrict__ down,
    const float* __restrict__ dlB, const float* __restrict__ ter2,
    const int* __restrict__ cnt, const int* __restrict__ list,
    float* __restrict__ osel) {
  const int id = blockIdx.x;                 // 0..2047
  const int e  = id & 7;
  const int m  = id >> 3;
  const int ct = m & 63;                     // 0..63
  const int st = m >> 6;                     // 0..3
  const int n = cnt[e];
  if (st * 128 >= n) return;
  const int tid = threadIdx.x;

  __shared__ unsigned short Ap[2][128 * 64];
  __shared__ unsigned short Bp[2][32 * 64];

  const int c0 = ct * 32;

  const unsigned short *aSrc0, *aSrc1;
  int aOff0, aOff1;
  {
    int row = tid >> 3, k16 = tid & 7;
    int p = list[e * 512 + min(st * 128 + row, n - 1)];
    aSrc0 = h + (size_t)p * 1024 + k16 * 8;
    aOff0 = row * 64 + ((k16 * 8) ^ ((row & 7) << 3));
    int slot = tid + 512;
    row = slot >> 3; k16 = slot & 7;
    p = list[e * 512 + min(st * 128 + row, n - 1)];
    aSrc1 = h + (size_t)p * 1024 + k16 * 8;
    aOff1 = row * 64 + ((k16 * 8) ^ ((row & 7) << 3));
  }
  // B: thread owns 4 cols x 1 k-row
  const int c4 = (tid & 7) * 4;              // 0..28
  const int kr = tid >> 3;                   // 0..63
  const float* bSrc = down + ((size_t)e * 1024 + kr) * 2048 + c0 + c4;
  int bOffc[4];
#pragma unroll
  for (int cc = 0; cc < 4; ++cc)
    bOffc[cc] = (c4 + cc) * 64 + (kr ^ (((c4 + cc) & 7) << 3));

  const int lane = tid & 63, wv = tid >> 6;
  const int lr = lane & 15, lh = lane >> 4;
  const int wr = wv >> 1, ni = wv & 1;

  uint4 a0A, a1A, a0B, a1B;
  float bA[4], bB[4];

#define G2_LOAD(SUF, T) {                                          \
    const int kk = (T) * 64;                                       \
    a0##SUF = *(const uint4*)(aSrc0 + kk);                         \
    a1##SUF = *(const uint4*)(aSrc1 + kk);                         \
    *(float4*)&b##SUF[0] = *(const float4*)(bSrc + (size_t)kk * 2048); }

#define G2_BODY(BUF, SUF, NXT) {                                               \
    *(uint4*)&Ap[BUF][aOff0] = a0##SUF;                                        \
    *(uint4*)&Ap[BUF][aOff1] = a1##SUF;                                        \
    _Pragma("unroll") for (int cc = 0; cc < 4; ++cc)                           \
      Bp[BUF][bOffc[cc]] = f2bf(b##SUF[cc]);                                   \
    PIPE_BARRIER();                                                            \
    if ((NXT) < 16) G2_LOAD(SUF, NXT);                                         \
    _Pragma("unroll") for (int ks = 0; ks < 64; ks += 32) {                    \
      int kb = ks + lh * 8;                                                    \
      s16x8 af[2], bd;                                                         \
      _Pragma("unroll") for (int q = 0; q < 2; ++q) {                          \
        int ar = wr * 32 + q * 16 + lr;                                        \
        af[q] = *(const s16x8*)&Ap[BUF][ar * 64 + (kb ^ ((ar & 7) << 3))];     \
      }                                                                        \
      { int bc = ni * 16 + lr;                                                 \
        bd = *(const s16x8*)&Bp[BUF][bc * 64 + (kb ^ ((bc & 7) << 3))]; }      \
      _Pragma("unroll") for (int q = 0; q < 2; ++q)                            \
        acc[q] = __builtin_amdgcn_mfma_f32_16x16x32_bf16(af[q], bd, acc[q], 0, 0, 0); \
    } }

  f32x4 acc[2] = {};
  G2_LOAD(A, 0);
  G2_LOAD(B, 1);
  for (int tt = 0; tt < 16; tt += 2) {
    G2_BODY(0, A, tt + 2);
    G2_BODY(1, B, tt + 3);
  }
#undef G2_LOAD
#undef G2_BODY

  // ---- epilogue: stage ter2 to LDS, fuse down-LoRA, store osel ----
  __syncthreads();
  float* t2l = (float*)&Ap[0][0];            // 128 x 16 f32
  for (int idx = tid; idx < 2048; idx += 512) {
    int row = idx >> 4, c = idx & 15;
    int p = list[e * 512 + min(st * 128 + row, n - 1)];
    t2l[idx] = ter2[p * 16 + c];
  }
  __syncthreads();
  {
    int yc = c0 + ni * 16 + lr;
    const float4* d4 = (const float4*)(dlB + ((size_t)e * 2048 + yc) * 16);
    float d2[16];
#pragma unroll
    for (int q = 0; q < 4; ++q) {
      float4 v = d4[q];
      d2[q*4+0]=v.x; d2[q*4+1]=v.y; d2[q*4+2]=v.z; d2[q*4+3]=v.w;
    }
#pragma unroll
    for (int q = 0; q < 2; ++q) {
#pragma unroll
      for (int j = 0; j < 4; ++j) {
        int row = wr * 32 + q * 16 + lh * 4 + j;
        if (st * 128 + row < n) {
          int p = list[e * 512 + st * 128 + row];
          const float* tv = &t2l[row * 16];
          float dd = 0.f;
#pragma unroll
          for (int rr = 0; rr < 16; ++rr) dd += tv[rr] * d2[rr];
          osel[(size_t)p * 2048 + yc] = acc[q][j] + 2.f * dd;
        }
      }
    }
  }
}

// y[t] = pw[2t]*osel[2t] + pw[2t+1]*osel[2t+1]
__global__ __launch_bounds__(256) void k_comb(
    const float* __restrict__ osel, const float* __restrict__ pw,
    float* __restrict__ y) {
  int i = blockIdx.x * 256 + threadIdx.x;     // float4 index, 262144 total
  int t = i >> 9;
  int c4 = i & 511;
  float w1 = pw[2 * t], w2 = pw[2 * t + 1];
  const float4* o = (const float4*)osel;
  float4 a = o[(size_t)(2 * t) * 512 + c4];
  float4 b = o[(size_t)(2 * t + 1) * 512 + c4];
  float4 rv;
  rv.x = w1 * a.x + w2 * b.x;
  rv.y = w1 * a.y + w2 * b.y;
  rv.z = w1 * a.z + w2 * b.z;
  rv.w = w1 * a.w + w2 * b.w;
  ((float4*)y)[i] = rv;
}

// ---------------------------------------------------------------------------
extern "C" void kernel_launch(void* const* d_in, const int* in_sizes, int n_in,
                              void* d_out, int out_size, void* d_ws, size_t ws_size,
                              hipStream_t stream) {
  (void)in_sizes; (void)n_in; (void)ws_size; (void)out_size;
  const float* x    = (const float*)d_in[0];
  const float* gw   = (const float*)d_in[1];
  const float* gA   = (const float*)d_in[2];
  const float* gB   = (const float*)d_in[3];
  const float* gup  = (const float*)d_in[4];
  const float* down = (const float*)d_in[5];
  const float* gupA = (const float*)d_in[6];
  const float* gupB = (const float*)d_in[7];
  const float* dlA  = (const float*)d_in[8];
  const float* dlB  = (const float*)d_in[9];
  float* y = (float*)d_out;

  char* w = (char*)d_ws;
  int*   cnt           = (int*)(w + OFF_CNT);
  float* ter1all       = (float*)(w + OFF_TER1A);
  float* ter2          = (float*)(w + OFF_TER2);
  int*   list          = (int*)(w + OFF_LIST);
  float* pw            = (float*)(w + OFF_PW);
  float* Wg            = (float*)(w + OFF_WG);
  unsigned short* xbf  = (unsigned short*)(w + OFF_XBF);
  unsigned short* hbuf = (unsigned short*)(w + OFF_H);
  float* osel          = (float*)(w + OFF_OSEL);

  hipMemsetAsync(w, 0, ZERO_SPAN, stream);

  k_gatecomb<<<64, 256, 0, stream>>>(gw, gA, gB, Wg);
  k_router<<<512, 256, 0, stream>>>(x, Wg, cnt, list, pw, xbf);
  k_ter1all<<<dim3(8, 4), 512, 0, stream>>>(xbf, gupA, ter1all);
  k_gemm1<<<1024, 512, 0, stream>>>(xbf, gup, gupB, ter1all, cnt, list, hbuf);
  k_ter2<<<dim3(4, 4, 8), 512, 0, stream>>>(hbuf, dlA, cnt, list, ter2);
  k_gemm2<<<2048, 512, 0, stream>>>(hbuf, down, dlB, ter2, cnt, list, osel);
  k_comb<<<1024, 256, 0, stream>>>(osel, pw, y);
}

// Round 8
// 133.620 us; speedup vs baseline: 1.0359x; 1.0359x over previous
//
#include <hip/hip_runtime.h>

// ---------------------------------------------------------------------------
// MoE gated MLP with LoRA, top-2 of 8, T=512, H=2048, I=1024, R=16.
// Round 8: 256-thread / BM=64 GEMM blocks (32KB LDS) for 4-5 co-resident
// blocks per CU (inter-block TLP to hide LLC latency). Staging pattern and
// 2-deep register pipeline retained from round 6.
// ---------------------------------------------------------------------------

typedef short  s16x8 __attribute__((ext_vector_type(8)));
typedef float  f32x4 __attribute__((ext_vector_type(4)));
typedef unsigned short u16x8 __attribute__((ext_vector_type(8)));

__device__ __forceinline__ unsigned short f2bf(float f) {
  unsigned u = __builtin_bit_cast(unsigned, f);
  u += 0x7fffu + ((u >> 16) & 1u);          // RNE
  return (unsigned short)(u >> 16);
}

// Barrier that does NOT drain vmcnt.
#define PIPE_BARRIER() asm volatile("s_waitcnt lgkmcnt(0)\n\ts_barrier" ::: "memory")

// ---- workspace layout (bytes). [0, ZERO_SPAN) memset to 0 each launch ----
#define OFF_CNT    0u          // 8 int (pad 256)
#define OFF_TER1A  256u        // 512*128 f32 = 262144
#define OFF_TER2   262400u     // 1024*16 f32 = 65536
#define ZERO_SPAN  327936u
#define OFF_LIST   327936u     // 8*512 int = 16384
#define OFF_PW     344320u     // 1024 f32 = 4096
#define OFF_WG     348416u     // 8*2048 f32 = 65536
#define OFF_XBF    413952u     // 512*2048 bf16 = 2097152
#define OFF_H      2511104u    // 1024*1024 bf16 = 2097152
#define OFF_OSEL   4608256u    // 1024*2048 f32 = 8388608
// total ~13.0 MB

// ---------------------------------------------------------------------------
__global__ void k_gatecomb(const float* __restrict__ gw, const float* __restrict__ gA,
                           const float* __restrict__ gB, float* __restrict__ Wg) {
  int idx = blockIdx.x * 256 + threadIdx.x;   // 16384
  int e = idx >> 11, h = idx & 2047;
  float acc = gw[idx];
#pragma unroll
  for (int r = 0; r < 16; ++r)
    acc += 2.0f * gB[e * 16 + r] * gA[r * 2048 + h];
  Wg[idx] = acc;
}

// fp32 router (exact logits -> identical top-k to reference) + fused x->bf16.
__global__ void k_router(const float* __restrict__ x, const float* __restrict__ Wg,
                         int* __restrict__ cnt, int* __restrict__ list,
                         float* __restrict__ pw, unsigned short* __restrict__ xbf) {
  int t = blockIdx.x, tid = threadIdx.x;
  __shared__ float xs[2048];
  __shared__ float logits[8];
  for (int i = tid; i < 2048; i += 256) xs[i] = x[(size_t)t * 2048 + i];
  __syncthreads();
  {
    u16x8 o;
#pragma unroll
    for (int j = 0; j < 8; ++j) o[j] = f2bf(xs[tid * 8 + j]);
    *(u16x8*)(xbf + (size_t)t * 2048 + tid * 8) = o;
  }
  int e = tid >> 5, l = tid & 31;
  float s = 0.f;
  for (int h = l; h < 2048; h += 32) s += xs[h] * Wg[e * 2048 + h];
#pragma unroll
  for (int off = 16; off >= 1; off >>= 1) s += __shfl_down(s, off, 32);
  if (l == 0) logits[e] = s;
  __syncthreads();
  if (tid == 0) {
    float m = logits[0];
#pragma unroll
    for (int i = 1; i < 8; ++i) m = fmaxf(m, logits[i]);
    float ex[8];
#pragma unroll
    for (int i = 0; i < 8; ++i) ex[i] = __expf(logits[i] - m);
    int e1 = 0; float v1 = ex[0];
#pragma unroll
    for (int i = 1; i < 8; ++i) if (ex[i] > v1) { v1 = ex[i]; e1 = i; }
    int e2 = -1; float v2 = -1.f;
#pragma unroll
    for (int i = 0; i < 8; ++i) if (i != e1 && ex[i] > v2) { v2 = ex[i]; e2 = i; }
    float inv = 1.f / (v1 + v2);
    int p1 = 2 * t, p2 = 2 * t + 1;
    pw[p1] = v1 * inv;
    pw[p2] = v2 * inv;
    int s1 = atomicAdd(&cnt[e1], 1); list[e1 * 512 + s1] = p1;
    int s2 = atomicAdd(&cnt[e2], 1); list[e2 * 512 + s2] = p2;
  }
}

// ter1all[t][er] = x[t] . gupA_flat[er]  (er = e*16+r). Round-2-proven.
__global__ __launch_bounds__(512) void k_ter1all(
    const unsigned short* __restrict__ xbf, const float* __restrict__ gupA,
    float* __restrict__ ter1all) {
  int trow = blockIdx.x, kcc = blockIdx.y;
  int tid = threadIdx.x;
  __shared__ unsigned short Ap[2][64 * 64];
  __shared__ unsigned short Bp[2][128 * 64];
  const int k0b = kcc * 512;

  int rowA = tid >> 3, k16A = tid & 7;
  const unsigned short* aSrc = xbf + (size_t)(trow * 64 + rowA) * 2048 + k0b + k16A * 8;
  int aOff = rowA * 64 + ((k16A * 8) ^ ((rowA & 7) << 3));

  const float* bSrc[2]; int bOff[2];
#pragma unroll
  for (int s = 0; s < 2; ++s) {
    int slot = tid + s * 512;
    int er = slot >> 3, kg = slot & 7;
    bSrc[s] = gupA + (size_t)er * 2048 + k0b + kg * 8;
    bOff[s] = er * 64 + ((kg * 8) ^ ((er & 7) << 3));
  }
  int lane = tid & 63, wv = tid >> 6;
  int lr = lane & 15, lh = lane >> 4;

  uint4 apre; float4 bpre[2][2];
#define TA_ISSUE(T) { int kk = (T) * 64;                                   \
    apre = *(const uint4*)(aSrc + kk);                                     \
    _Pragma("unroll") for (int s = 0; s < 2; ++s) {                        \
      bpre[s][0] = *(const float4*)(bSrc[s] + kk);                         \
      bpre[s][1] = *(const float4*)(bSrc[s] + kk + 4); } }

  f32x4 acc[4] = {};
  TA_ISSUE(0);
  for (int t = 0; t < 8; ++t) {
    int buf = t & 1;
    *(uint4*)&Ap[buf][aOff] = apre;
#pragma unroll
    for (int s = 0; s < 2; ++s) {
      u16x8 o;
      o[0]=f2bf(bpre[s][0].x); o[1]=f2bf(bpre[s][0].y); o[2]=f2bf(bpre[s][0].z); o[3]=f2bf(bpre[s][0].w);
      o[4]=f2bf(bpre[s][1].x); o[5]=f2bf(bpre[s][1].y); o[6]=f2bf(bpre[s][1].z); o[7]=f2bf(bpre[s][1].w);
      *(u16x8*)&Bp[buf][bOff[s]] = o;
    }
    __syncthreads();
    if (t < 7) TA_ISSUE(t + 1);
#pragma unroll
    for (int ks = 0; ks < 64; ks += 32) {
      int kb = ks + lh * 8;
      int bc = wv * 16 + lr;
      s16x8 b = *(const s16x8*)&Bp[buf][bc * 64 + (kb ^ ((bc & 7) << 3))];
#pragma unroll
      for (int fr = 0; fr < 4; ++fr) {
        int ar = fr * 16 + lr;
        s16x8 a = *(const s16x8*)&Ap[buf][ar * 64 + (kb ^ ((ar & 7) << 3))];
        acc[fr] = __builtin_amdgcn_mfma_f32_16x16x32_bf16(a, b, acc[fr], 0, 0, 0);
      }
    }
    __syncthreads();
  }
#undef TA_ISSUE
#pragma unroll
  for (int fr = 0; fr < 4; ++fr)
#pragma unroll
    for (int j = 0; j < 4; ++j) {
      int tok = trow * 64 + fr * 16 + lh * 4 + j;
      atomicAdd(&ter1all[tok * 128 + wv * 16 + lr], acc[fr][j]);
    }
}

// ---------------------------------------------------------------------------
// GEMM1: gathered x rows [BM=64] x gup[e], B-tile = 32 gate + 32 up cols,
// full K=2048 (NT=32). 256 threads = 4 waves (2M x 2N); 32KB LDS.
// id = e + 8*(ct + 32*st): expert e -> XCD e (A-panel L2-resident).
__global__ __launch_bounds__(256) void k_gemm1(
    const unsigned short* __restrict__ xbf, const float* __restrict__ gup,
    const float* __restrict__ gupB, const float* __restrict__ ter1all,
    const int* __restrict__ cnt, const int* __restrict__ list,
    unsigned short* __restrict__ h) {
  const int id = blockIdx.x;                 // 0..2047
  const int e  = id & 7;
  const int m  = id >> 3;
  const int ct = m & 31;                     // i-cols [ct*32, ct*32+32)
  const int st = m >> 5;                     // 0..7 : token slice of 64
  const int n = cnt[e];
  if (st * 64 >= n) return;
  const int tid = threadIdx.x;

  __shared__ unsigned short Ap[2][64 * 64];    // [row][k] swizzled, 8KB each
  __shared__ unsigned short Bp[2][64 * 64];    // [col][k]: 0..31 gate, 32..63 up

  const int c0 = ct * 32;

  // A: 64 rows x 8 k-chunks = 512 slots; thread handles tid and tid+256
  const unsigned short *aSrc0, *aSrc1;
  int aOff0, aOff1;
  {
    int row = tid >> 3, k16 = tid & 7;
    int p = list[e * 512 + min(st * 64 + row, n - 1)];
    aSrc0 = xbf + (size_t)(p >> 1) * 2048 + k16 * 8;
    aOff0 = row * 64 + ((k16 * 8) ^ ((row & 7) << 3));
    int slot = tid + 256;
    row = slot >> 3; k16 = slot & 7;
    p = list[e * 512 + min(st * 64 + row, n - 1)];
    aSrc1 = xbf + (size_t)(p >> 1) * 2048 + k16 * 8;
    aOff1 = row * 64 + ((k16 * 8) ^ ((row & 7) << 3));
  }
  // B: thread owns 1 col x 16 k-rows (scalar strided loads, proven pattern)
  const int bcol = tid & 63, kgrp = tid >> 6;    // kgrp in 0..3
  const int gcol = (bcol < 32) ? (c0 + bcol) : (1024 + c0 + bcol - 32);
  const float* bSrc = gup + (size_t)e * 2048 * 2048 + (size_t)(kgrp * 16) * 2048 + gcol;
  const int sw = (bcol & 7) << 3;
  const int bOff0 = bcol * 64 + ((kgrp * 16) ^ sw);
  const int bOff1 = bcol * 64 + ((kgrp * 16 + 8) ^ sw);

  const int lane = tid & 63, wv = tid >> 6;
  const int lr = lane & 15, lh = lane >> 4;
  const int wr = wv >> 1, ni = wv & 1;       // 2M x 2N waves

  uint4 a0A, a1A, a0B, a1B;
  float bA[16], bB[16];

#define G1_LOAD(SUF, T) {                                        \
    const int kk = (T) * 64;                                     \
    a0##SUF = *(const uint4*)(aSrc0 + kk);                       \
    a1##SUF = *(const uint4*)(aSrc1 + kk);                       \
    _Pragma("unroll") for (int j = 0; j < 16; ++j)               \
      b##SUF[j] = bSrc[(size_t)(kk + j) * 2048]; }

#define G1_BODY(BUF, SUF, NXT) {                                               \
    *(uint4*)&Ap[BUF][aOff0] = a0##SUF;                                        \
    *(uint4*)&Ap[BUF][aOff1] = a1##SUF;                                        \
    { u16x8 o0, o1;                                                            \
      _Pragma("unroll") for (int j = 0; j < 8; ++j) {                          \
        o0[j] = f2bf(b##SUF[j]); o1[j] = f2bf(b##SUF[j + 8]); }                \
      *(u16x8*)&Bp[BUF][bOff0] = o0;                                           \
      *(u16x8*)&Bp[BUF][bOff1] = o1; }                                         \
    PIPE_BARRIER();                                                            \
    if ((NXT) < 32) G1_LOAD(SUF, NXT);                                         \
    _Pragma("unroll") for (int ks = 0; ks < 64; ks += 32) {                    \
      int kb = ks + lh * 8;                                                    \
      s16x8 af[2], bg, bu;                                                     \
      _Pragma("unroll") for (int q = 0; q < 2; ++q) {                          \
        int ar = wr * 32 + q * 16 + lr;                                        \
        af[q] = *(const s16x8*)&Ap[BUF][ar * 64 + (kb ^ ((ar & 7) << 3))];     \
      }                                                                        \
      { int bc = ni * 16 + lr;                                                 \
        bg = *(const s16x8*)&Bp[BUF][bc * 64 + (kb ^ ((bc & 7) << 3))];        \
        int bc2 = bc + 32;                                                     \
        bu = *(const s16x8*)&Bp[BUF][bc2 * 64 + (kb ^ ((bc2 & 7) << 3))]; }    \
      _Pragma("unroll") for (int q = 0; q < 2; ++q) {                          \
        accg[q] = __builtin_amdgcn_mfma_f32_16x16x32_bf16(af[q], bg, accg[q], 0, 0, 0); \
        accu[q] = __builtin_amdgcn_mfma_f32_16x16x32_bf16(af[q], bu, accu[q], 0, 0, 0); \
      }                                                                        \
    } }

  f32x4 accg[2] = {}, accu[2] = {};
  G1_LOAD(A, 0);
  G1_LOAD(B, 1);
  for (int tt = 0; tt < 32; tt += 2) {
    G1_BODY(0, A, tt + 2);
    G1_BODY(1, B, tt + 3);
  }
#undef G1_LOAD
#undef G1_BODY

  // ---- epilogue: stage ter1 rows to LDS, fuse LoRA + silu, store bf16 h ----
  __syncthreads();
  float* tlds = (float*)&Ap[0][0];             // 64 x 16 f32 = 4KB
  for (int idx = tid; idx < 1024; idx += 256) {
    int row = idx >> 4, c = idx & 15;
    int p = list[e * 512 + min(st * 64 + row, n - 1)];
    tlds[idx] = ter1all[(size_t)(p >> 1) * 128 + e * 16 + c];
  }
  __syncthreads();
  {
    int gc = c0 + ni * 16 + lr;                // global i-col 0..1023
    const float4* g4 = (const float4*)(gupB + ((size_t)e * 2048 + gc) * 16);
    const float4* u4 = (const float4*)(gupB + ((size_t)e * 2048 + 1024 + gc) * 16);
    float gv2[16], uv2[16];
#pragma unroll
    for (int q = 0; q < 4; ++q) {
      float4 gv = g4[q], uv = u4[q];
      gv2[q*4+0]=gv.x; gv2[q*4+1]=gv.y; gv2[q*4+2]=gv.z; gv2[q*4+3]=gv.w;
      uv2[q*4+0]=uv.x; uv2[q*4+1]=uv.y; uv2[q*4+2]=uv.z; uv2[q*4+3]=uv.w;
    }
#pragma unroll
    for (int q = 0; q < 2; ++q) {
#pragma unroll
      for (int j = 0; j < 4; ++j) {
        int row = wr * 32 + q * 16 + lh * 4 + j;
        if (st * 64 + row < n) {
          int p = list[e * 512 + st * 64 + row];
          const float* tv = &tlds[row * 16];
          float dg = 0.f, du = 0.f;
#pragma unroll
          for (int rr = 0; rr < 16; ++rr) { dg += tv[rr] * gv2[rr]; du += tv[rr] * uv2[rr]; }
          float g = accg[q][j] + 2.f * dg;
          float u = accu[q][j] + 2.f * du;
          h[(size_t)p * 1024 + gc] = f2bf(g / (1.f + __expf(-g)) * u);
        }
      }
    }
  }
}

// ter2[p][r] = h[p] . dlA[e][r], grouped MFMA GEMM (BN=16), split-K=4.
__global__ __launch_bounds__(512) void k_ter2(
    const unsigned short* __restrict__ h, const float* __restrict__ dlA,
    const int* __restrict__ cnt, const int* __restrict__ list,
    float* __restrict__ ter2) {
  int st = blockIdx.x, kcc = blockIdx.y, e = blockIdx.z;
  int n = cnt[e];
  if (st * 128 >= n) return;
  int tid = threadIdx.x;
  __shared__ unsigned short Ap[2][128 * 64];
  __shared__ unsigned short Bp[2][16 * 64];
  const int k0b = kcc * 256;

  const unsigned short* aSrc[2]; int aOff[2];
#pragma unroll
  for (int s = 0; s < 2; ++s) {
    int slot = tid + s * 512;
    int row = slot >> 3, k16 = slot & 7;
    int p = list[e * 512 + min(st * 128 + row, n - 1)];
    aSrc[s] = h + (size_t)p * 1024 + k0b + k16 * 8;
    aOff[s] = row * 64 + ((k16 * 8) ^ ((row & 7) << 3));
  }
  const float* bSrc = nullptr; int bOff = 0;
  if (tid < 128) {
    int r = tid >> 3, kg = tid & 7;
    bSrc = dlA + ((size_t)e * 16 + r) * 1024 + k0b + kg * 8;
    bOff = r * 64 + ((kg * 8) ^ ((r & 7) << 3));
  }
  int lane = tid & 63, wv = tid >> 6;
  int lr = lane & 15, lh = lane >> 4;

  uint4 apre[2]; float4 bpre[2];
#define T2_ISSUE(T) { int kk = (T) * 64;                                   \
    _Pragma("unroll") for (int s = 0; s < 2; ++s)                          \
        apre[s] = *(const uint4*)(aSrc[s] + kk);                           \
    if (tid < 128) { bpre[0] = *(const float4*)(bSrc + kk);                \
                     bpre[1] = *(const float4*)(bSrc + kk + 4); } }

  f32x4 acc = {};
  T2_ISSUE(0);
  for (int t = 0; t < 4; ++t) {
    int buf = t & 1;
#pragma unroll
    for (int s = 0; s < 2; ++s) *(uint4*)&Ap[buf][aOff[s]] = apre[s];
    if (tid < 128) {
      u16x8 o;
      o[0]=f2bf(bpre[0].x); o[1]=f2bf(bpre[0].y); o[2]=f2bf(bpre[0].z); o[3]=f2bf(bpre[0].w);
      o[4]=f2bf(bpre[1].x); o[5]=f2bf(bpre[1].y); o[6]=f2bf(bpre[1].z); o[7]=f2bf(bpre[1].w);
      *(u16x8*)&Bp[buf][bOff] = o;
    }
    __syncthreads();
    if (t < 3) T2_ISSUE(t + 1);
#pragma unroll
    for (int ks = 0; ks < 64; ks += 32) {
      int kb = ks + lh * 8;
      s16x8 b = *(const s16x8*)&Bp[buf][lr * 64 + (kb ^ ((lr & 7) << 3))];
      int ar = wv * 16 + lr;
      s16x8 a = *(const s16x8*)&Ap[buf][ar * 64 + (kb ^ ((ar & 7) << 3))];
      acc = __builtin_amdgcn_mfma_f32_16x16x32_bf16(a, b, acc, 0, 0, 0);
    }
    __syncthreads();
  }
#undef T2_ISSUE
#pragma unroll
  for (int j = 0; j < 4; ++j) {
    int row = wv * 16 + lh * 4 + j;
    if (st * 128 + row < n) {
      int p = list[e * 512 + st * 128 + row];
      atomicAdd(&ter2[p * 16 + lr], acc[j]);
    }
  }
}

// GEMM2: gathered h rows [BM=64] x down[e] [BN=64], full K=1024 (NT=16).
// 256 threads = 4 waves (2M x 2N); 32KB LDS. id = e + 8*(ct + 32*st).
// Epilogue fuses down-LoRA, stores per-slot osel.
__global__ __launch_bounds__(256) void k_gemm2(
    const unsigned short* __restrict__ h, const float* __restrict__ down,
    const float* __restrict__ dlB, const float* __restrict__ ter2,
    const int* __restrict__ cnt, const int* __restrict__ list,
    float* __restrict__ osel) {
  const int id = blockIdx.x;                 // 0..2047
  const int e  = id & 7;
  const int m  = id >> 3;
  const int ct = m & 31;                     // out-cols [ct*64, ct*64+64)
  const int st = m >> 5;                     // 0..7
  const int n = cnt[e];
  if (st * 64 >= n) return;
  const int tid = threadIdx.x;

  __shared__ unsigned short Ap[2][64 * 64];
  __shared__ unsigned short Bp[2][64 * 64];

  const int c0 = ct * 64;

  const unsigned short *aSrc0, *aSrc1;
  int aOff0, aOff1;
  {
    int row = tid >> 3, k16 = tid & 7;
    int p = list[e * 512 + min(st * 64 + row, n - 1)];
    aSrc0 = h + (size_t)p * 1024 + k16 * 8;
    aOff0 = row * 64 + ((k16 * 8) ^ ((row & 7) << 3));
    int slot = tid + 256;
    row = slot >> 3; k16 = slot & 7;
    p = list[e * 512 + min(st * 64 + row, n - 1)];
    aSrc1 = h + (size_t)p * 1024 + k16 * 8;
    aOff1 = row * 64 + ((k16 * 8) ^ ((row & 7) << 3));
  }
  const int bcol = tid & 63, kgrp = tid >> 6;
  const float* bSrc = down + ((size_t)e * 1024 + kgrp * 16) * 2048 + c0 + bcol;
  const int sw = (bcol & 7) << 3;
  const int bOff0 = bcol * 64 + ((kgrp * 16) ^ sw);
  const int bOff1 = bcol * 64 + ((kgrp * 16 + 8) ^ sw);

  const int lane = tid & 63, wv = tid >> 6;
  const int lr = lane & 15, lh = lane >> 4;
  const int wr = wv >> 1, nc = wv & 1;

  uint4 a0A, a1A, a0B, a1B;
  float bA[16], bB[16];

#define G2_LOAD(SUF, T) {                                        \
    const int kk = (T) * 64;                                     \
    a0##SUF = *(const uint4*)(aSrc0 + kk);                       \
    a1##SUF = *(const uint4*)(aSrc1 + kk);                       \
    _Pragma("unroll") for (int j = 0; j < 16; ++j)               \
      b##SUF[j] = bSrc[(size_t)(kk + j) * 2048]; }

#define G2_BODY(BUF, SUF, NXT) {                                               \
    *(uint4*)&Ap[BUF][aOff0] = a0##SUF;                                        \
    *(uint4*)&Ap[BUF][aOff1] = a1##SUF;                                        \
    { u16x8 o0, o1;                                                            \
      _Pragma("unroll") for (int j = 0; j < 8; ++j) {                          \
        o0[j] = f2bf(b##SUF[j]); o1[j] = f2bf(b##SUF[j + 8]); }                \
      *(u16x8*)&Bp[BUF][bOff0] = o0;                                           \
      *(u16x8*)&Bp[BUF][bOff1] = o1; }                                         \
    PIPE_BARRIER();                                                            \
    if ((NXT) < 16) G2_LOAD(SUF, NXT);                                         \
    _Pragma("unroll") for (int ks = 0; ks < 64; ks += 32) {                    \
      int kb = ks + lh * 8;                                                    \
      s16x8 af[2], bd[2];                                                      \
      _Pragma("unroll") for (int q = 0; q < 2; ++q) {                          \
        int ar = wr * 32 + q * 16 + lr;                                        \
        af[q] = *(const s16x8*)&Ap[BUF][ar * 64 + (kb ^ ((ar & 7) << 3))];     \
      }                                                                        \
      _Pragma("unroll") for (int r = 0; r < 2; ++r) {                          \
        int bc = nc * 32 + r * 16 + lr;                                        \
        bd[r] = *(const s16x8*)&Bp[BUF][bc * 64 + (kb ^ ((bc & 7) << 3))];     \
      }                                                                        \
      _Pragma("unroll") for (int q = 0; q < 2; ++q)                            \
        _Pragma("unroll") for (int r = 0; r < 2; ++r)                          \
          acc[q][r] = __builtin_amdgcn_mfma_f32_16x16x32_bf16(af[q], bd[r], acc[q][r], 0, 0, 0); \
    } }

  f32x4 acc[2][2] = {};
  G2_LOAD(A, 0);
  G2_LOAD(B, 1);
  for (int tt = 0; tt < 16; tt += 2) {
    G2_BODY(0, A, tt + 2);
    G2_BODY(1, B, tt + 3);
  }
#undef G2_LOAD
#undef G2_BODY

  // ---- epilogue: stage ter2 to LDS, fuse down-LoRA, store osel ----
  __syncthreads();
  float* t2l = (float*)&Ap[0][0];            // 64 x 16 f32
  for (int idx = tid; idx < 1024; idx += 256) {
    int row = idx >> 4, c = idx & 15;
    int p = list[e * 512 + min(st * 64 + row, n - 1)];
    t2l[idx] = ter2[p * 16 + c];
  }
  __syncthreads();
#pragma unroll
  for (int r = 0; r < 2; ++r) {
    int yc = c0 + nc * 32 + r * 16 + lr;
    const float4* d4 = (const float4*)(dlB + ((size_t)e * 2048 + yc) * 16);
    float d2[16];
#pragma unroll
    for (int q = 0; q < 4; ++q) {
      float4 v = d4[q];
      d2[q*4+0]=v.x; d2[q*4+1]=v.y; d2[q*4+2]=v.z; d2[q*4+3]=v.w;
    }
#pragma unroll
    for (int q = 0; q < 2; ++q) {
#pragma unroll
      for (int j = 0; j < 4; ++j) {
        int row = wr * 32 + q * 16 + lh * 4 + j;
        if (st * 64 + row < n) {
          int p = list[e * 512 + st * 64 + row];
          const float* tv = &t2l[row * 16];
          float dd = 0.f;
#pragma unroll
          for (int rr = 0; rr < 16; ++rr) dd += tv[rr] * d2[rr];
          osel[(size_t)p * 2048 + yc] = acc[q][r][j] + 2.f * dd;
        }
      }
    }
  }
}

// y[t] = pw[2t]*osel[2t] + pw[2t+1]*osel[2t+1]
__global__ __launch_bounds__(256) void k_comb(
    const float* __restrict__ osel, const float* __restrict__ pw,
    float* __restrict__ y) {
  int i = blockIdx.x * 256 + threadIdx.x;     // float4 index, 262144 total
  int t = i >> 9;
  int c4 = i & 511;
  float w1 = pw[2 * t], w2 = pw[2 * t + 1];
  const float4* o = (const float4*)osel;
  float4 a = o[(size_t)(2 * t) * 512 + c4];
  float4 b = o[(size_t)(2 * t + 1) * 512 + c4];
  float4 rv;
  rv.x = w1 * a.x + w2 * b.x;
  rv.y = w1 * a.y + w2 * b.y;
  rv.z = w1 * a.z + w2 * b.z;
  rv.w = w1 * a.w + w2 * b.w;
  ((float4*)y)[i] = rv;
}

// ---------------------------------------------------------------------------
extern "C" void kernel_launch(void* const* d_in, const int* in_sizes, int n_in,
                              void* d_out, int out_size, void* d_ws, size_t ws_size,
                              hipStream_t stream) {
  (void)in_sizes; (void)n_in; (void)ws_size; (void)out_size;
  const float* x    = (const float*)d_in[0];
  const float* gw   = (const float*)d_in[1];
  const float* gA   = (const float*)d_in[2];
  const float* gB   = (const float*)d_in[3];
  const float* gup  = (const float*)d_in[4];
  const float* down = (const float*)d_in[5];
  const float* gupA = (const float*)d_in[6];
  const float* gupB = (const float*)d_in[7];
  const float* dlA  = (const float*)d_in[8];
  const float* dlB  = (const float*)d_in[9];
  float* y = (float*)d_out;

  char* w = (char*)d_ws;
  int*   cnt           = (int*)(w + OFF_CNT);
  float* ter1all       = (float*)(w + OFF_TER1A);
  float* ter2          = (float*)(w + OFF_TER2);
  int*   list          = (int*)(w + OFF_LIST);
  float* pw            = (float*)(w + OFF_PW);
  float* Wg            = (float*)(w + OFF_WG);
  unsigned short* xbf  = (unsigned short*)(w + OFF_XBF);
  unsigned short* hbuf = (unsigned short*)(w + OFF_H);
  float* osel          = (float*)(w + OFF_OSEL);

  hipMemsetAsync(w, 0, ZERO_SPAN, stream);

  k_gatecomb<<<64, 256, 0, stream>>>(gw, gA, gB, Wg);
  k_router<<<512, 256, 0, stream>>>(x, Wg, cnt, list, pw, xbf);
  k_ter1all<<<dim3(8, 4), 512, 0, stream>>>(xbf, gupA, ter1all);
  k_gemm1<<<2048, 256, 0, stream>>>(xbf, gup, gupB, ter1all, cnt, list, hbuf);
  k_ter2<<<dim3(4, 4, 8), 512, 0, stream>>>(hbuf, dlA, cnt, list, ter2);
  k_gemm2<<<2048, 256, 0, stream>>>(hbuf, down, dlB, ter2, cnt, list, osel);
  k_comb<<<1024, 256, 0, stream>>>(osel, pw, y);
}

// Round 9
// 129.317 us; speedup vs baseline: 1.0704x; 1.0333x over previous
//
#include <hip/hip_runtime.h>

// ---------------------------------------------------------------------------
// MoE gated MLP with LoRA, top-2 of 8, T=512, H=2048, I=1024, R=16.
// Round 9: round-6 structure, GEMM pipeline depth 2 -> 3 (three static
// register sets, 6-body unroll): load -> ds_write spans 2 full bodies, so
// the counted vmcnt covers ~LLC latency. Single-variable change vs round 6.
// ---------------------------------------------------------------------------

typedef short  s16x8 __attribute__((ext_vector_type(8)));
typedef float  f32x4 __attribute__((ext_vector_type(4)));
typedef unsigned short u16x8 __attribute__((ext_vector_type(8)));

__device__ __forceinline__ unsigned short f2bf(float f) {
  unsigned u = __builtin_bit_cast(unsigned, f);
  u += 0x7fffu + ((u >> 16) & 1u);          // RNE
  return (unsigned short)(u >> 16);
}

// Barrier that does NOT drain vmcnt.
#define PIPE_BARRIER() asm volatile("s_waitcnt lgkmcnt(0)\n\ts_barrier" ::: "memory")

// ---- workspace layout (bytes). [0, ZERO_SPAN) memset to 0 each launch ----
#define OFF_CNT    0u          // 8 int (pad 256)
#define OFF_TER1A  256u        // 512*128 f32 = 262144
#define OFF_TER2   262400u     // 1024*16 f32 = 65536
#define ZERO_SPAN  327936u
#define OFF_LIST   327936u     // 8*512 int = 16384
#define OFF_PW     344320u     // 1024 f32 = 4096
#define OFF_WG     348416u     // 8*2048 f32 = 65536
#define OFF_XBF    413952u     // 512*2048 bf16 = 2097152
#define OFF_H      2511104u    // 1024*1024 bf16 = 2097152
#define OFF_OSEL   4608256u    // 1024*2048 f32 = 8388608
// total ~13.0 MB

// ---------------------------------------------------------------------------
__global__ void k_gatecomb(const float* __restrict__ gw, const float* __restrict__ gA,
                           const float* __restrict__ gB, float* __restrict__ Wg) {
  int idx = blockIdx.x * 256 + threadIdx.x;   // 16384
  int e = idx >> 11, h = idx & 2047;
  float acc = gw[idx];
#pragma unroll
  for (int r = 0; r < 16; ++r)
    acc += 2.0f * gB[e * 16 + r] * gA[r * 2048 + h];
  Wg[idx] = acc;
}

// fp32 router (exact logits -> identical top-k to reference) + fused x->bf16.
__global__ void k_router(const float* __restrict__ x, const float* __restrict__ Wg,
                         int* __restrict__ cnt, int* __restrict__ list,
                         float* __restrict__ pw, unsigned short* __restrict__ xbf) {
  int t = blockIdx.x, tid = threadIdx.x;
  __shared__ float xs[2048];
  __shared__ float logits[8];
  for (int i = tid; i < 2048; i += 256) xs[i] = x[(size_t)t * 2048 + i];
  __syncthreads();
  {
    u16x8 o;
#pragma unroll
    for (int j = 0; j < 8; ++j) o[j] = f2bf(xs[tid * 8 + j]);
    *(u16x8*)(xbf + (size_t)t * 2048 + tid * 8) = o;
  }
  int e = tid >> 5, l = tid & 31;
  float s = 0.f;
  for (int h = l; h < 2048; h += 32) s += xs[h] * Wg[e * 2048 + h];
#pragma unroll
  for (int off = 16; off >= 1; off >>= 1) s += __shfl_down(s, off, 32);
  if (l == 0) logits[e] = s;
  __syncthreads();
  if (tid == 0) {
    float m = logits[0];
#pragma unroll
    for (int i = 1; i < 8; ++i) m = fmaxf(m, logits[i]);
    float ex[8];
#pragma unroll
    for (int i = 0; i < 8; ++i) ex[i] = __expf(logits[i] - m);
    int e1 = 0; float v1 = ex[0];
#pragma unroll
    for (int i = 1; i < 8; ++i) if (ex[i] > v1) { v1 = ex[i]; e1 = i; }
    int e2 = -1; float v2 = -1.f;
#pragma unroll
    for (int i = 0; i < 8; ++i) if (i != e1 && ex[i] > v2) { v2 = ex[i]; e2 = i; }
    float inv = 1.f / (v1 + v2);
    int p1 = 2 * t, p2 = 2 * t + 1;
    pw[p1] = v1 * inv;
    pw[p2] = v2 * inv;
    int s1 = atomicAdd(&cnt[e1], 1); list[e1 * 512 + s1] = p1;
    int s2 = atomicAdd(&cnt[e2], 1); list[e2 * 512 + s2] = p2;
  }
}

// ter1all[t][er] = x[t] . gupA_flat[er]  (er = e*16+r). Round-2-proven.
__global__ __launch_bounds__(512) void k_ter1all(
    const unsigned short* __restrict__ xbf, const float* __restrict__ gupA,
    float* __restrict__ ter1all) {
  int trow = blockIdx.x, kcc = blockIdx.y;
  int tid = threadIdx.x;
  __shared__ unsigned short Ap[2][64 * 64];
  __shared__ unsigned short Bp[2][128 * 64];
  const int k0b = kcc * 512;

  int rowA = tid >> 3, k16A = tid & 7;
  const unsigned short* aSrc = xbf + (size_t)(trow * 64 + rowA) * 2048 + k0b + k16A * 8;
  int aOff = rowA * 64 + ((k16A * 8) ^ ((rowA & 7) << 3));

  const float* bSrc[2]; int bOff[2];
#pragma unroll
  for (int s = 0; s < 2; ++s) {
    int slot = tid + s * 512;
    int er = slot >> 3, kg = slot & 7;
    bSrc[s] = gupA + (size_t)er * 2048 + k0b + kg * 8;
    bOff[s] = er * 64 + ((kg * 8) ^ ((er & 7) << 3));
  }
  int lane = tid & 63, wv = tid >> 6;
  int lr = lane & 15, lh = lane >> 4;

  uint4 apre; float4 bpre[2][2];
#define TA_ISSUE(T) { int kk = (T) * 64;                                   \
    apre = *(const uint4*)(aSrc + kk);                                     \
    _Pragma("unroll") for (int s = 0; s < 2; ++s) {                        \
      bpre[s][0] = *(const float4*)(bSrc[s] + kk);                         \
      bpre[s][1] = *(const float4*)(bSrc[s] + kk + 4); } }

  f32x4 acc[4] = {};
  TA_ISSUE(0);
  for (int t = 0; t < 8; ++t) {
    int buf = t & 1;
    *(uint4*)&Ap[buf][aOff] = apre;
#pragma unroll
    for (int s = 0; s < 2; ++s) {
      u16x8 o;
      o[0]=f2bf(bpre[s][0].x); o[1]=f2bf(bpre[s][0].y); o[2]=f2bf(bpre[s][0].z); o[3]=f2bf(bpre[s][0].w);
      o[4]=f2bf(bpre[s][1].x); o[5]=f2bf(bpre[s][1].y); o[6]=f2bf(bpre[s][1].z); o[7]=f2bf(bpre[s][1].w);
      *(u16x8*)&Bp[buf][bOff[s]] = o;
    }
    __syncthreads();
    if (t < 7) TA_ISSUE(t + 1);
#pragma unroll
    for (int ks = 0; ks < 64; ks += 32) {
      int kb = ks + lh * 8;
      int bc = wv * 16 + lr;
      s16x8 b = *(const s16x8*)&Bp[buf][bc * 64 + (kb ^ ((bc & 7) << 3))];
#pragma unroll
      for (int fr = 0; fr < 4; ++fr) {
        int ar = fr * 16 + lr;
        s16x8 a = *(const s16x8*)&Ap[buf][ar * 64 + (kb ^ ((ar & 7) << 3))];
        acc[fr] = __builtin_amdgcn_mfma_f32_16x16x32_bf16(a, b, acc[fr], 0, 0, 0);
      }
    }
    __syncthreads();
  }
#undef TA_ISSUE
#pragma unroll
  for (int fr = 0; fr < 4; ++fr)
#pragma unroll
    for (int j = 0; j < 4; ++j) {
      int tok = trow * 64 + fr * 16 + lh * 4 + j;
      atomicAdd(&ter1all[tok * 128 + wv * 16 + lr], acc[fr][j]);
    }
}

// ---------------------------------------------------------------------------
// GEMM1: gathered x rows [BM=128] x gup[e], B-tile = 64 gate + 64 up cols,
// full K=2048 (NT=32). 3-deep register pipeline (sets A/B/C), 2 LDS bufs.
__global__ __launch_bounds__(512) void k_gemm1(
    const unsigned short* __restrict__ xbf, const float* __restrict__ gup,
    const float* __restrict__ gupB, const float* __restrict__ ter1all,
    const int* __restrict__ cnt, const int* __restrict__ list,
    unsigned short* __restrict__ h) {
  const int ct = blockIdx.x;                 // 0..15 : i-cols [ct*64, ct*64+64)
  const int st = blockIdx.y;                 // 0..3
  const int e  = blockIdx.z;
  const int n = cnt[e];
  if (st * 128 >= n) return;
  const int tid = threadIdx.x;

  __shared__ unsigned short Ap[2][128 * 64];   // [row][k] swizzled
  __shared__ unsigned short Bp[2][128 * 64];   // [col][k]: 0..63 gate, 64..127 up

  const int c0 = ct * 64;

  const unsigned short *aSrc0, *aSrc1;
  int aOff0, aOff1;
  {
    int row = tid >> 3, k16 = tid & 7;
    int p = list[e * 512 + min(st * 128 + row, n - 1)];
    aSrc0 = xbf + (size_t)(p >> 1) * 2048 + k16 * 8;
    aOff0 = row * 64 + ((k16 * 8) ^ ((row & 7) << 3));
    int slot = tid + 512;
    row = slot >> 3; k16 = slot & 7;
    p = list[e * 512 + min(st * 128 + row, n - 1)];
    aSrc1 = xbf + (size_t)(p >> 1) * 2048 + k16 * 8;
    aOff1 = row * 64 + ((k16 * 8) ^ ((row & 7) << 3));
  }
  // B: col 0..127; global col = gate c0+col (col<64) else up 1024+c0+col-64
  const int bcol = tid & 127, kgrp = tid >> 7;   // 4 k-groups of 16
  const int gcg = (bcol < 64) ? (c0 + bcol) : (1024 + c0 + bcol - 64);
  const float* bSrc = gup + (size_t)e * 2048 * 2048 + (size_t)(kgrp * 16) * 2048 + gcg;
  const int sw = (bcol & 7) << 3;
  const int bOff0 = bcol * 64 + ((kgrp * 16) ^ sw);
  const int bOff1 = bcol * 64 + ((kgrp * 16 + 8) ^ sw);

  const int lane = tid & 63, wv = tid >> 6;
  const int lr = lane & 15, lh = lane >> 4;
  const int wr = wv >> 1, ni = wv & 1;       // 4 M-waves x 2 N-waves

  uint4 a0A, a1A, a0B, a1B, a0C, a1C;
  float bA[16], bB[16], bC[16];

#define G1_LOAD(SUF, T) {                                        \
    const int kk = (T) * 64;                                     \
    a0##SUF = *(const uint4*)(aSrc0 + kk);                       \
    a1##SUF = *(const uint4*)(aSrc1 + kk);                       \
    _Pragma("unroll") for (int j = 0; j < 16; ++j)               \
      b##SUF[j] = bSrc[(size_t)(kk + j) * 2048]; }

#define G1_BODY(BUF, SUF, NXT) {                                               \
    *(uint4*)&Ap[BUF][aOff0] = a0##SUF;                                        \
    *(uint4*)&Ap[BUF][aOff1] = a1##SUF;                                        \
    { u16x8 o0, o1;                                                            \
      _Pragma("unroll") for (int j = 0; j < 8; ++j) {                          \
        o0[j] = f2bf(b##SUF[j]); o1[j] = f2bf(b##SUF[j + 8]); }                \
      *(u16x8*)&Bp[BUF][bOff0] = o0;                                           \
      *(u16x8*)&Bp[BUF][bOff1] = o1; }                                         \
    PIPE_BARRIER();                                                            \
    if ((NXT) < 32) G1_LOAD(SUF, NXT);                                         \
    _Pragma("unroll") for (int ks = 0; ks < 64; ks += 32) {                    \
      int kb = ks + lh * 8;                                                    \
      s16x8 af[2], bg[2], bu[2];                                               \
      _Pragma("unroll") for (int q = 0; q < 2; ++q) {                          \
        int ar = wr * 32 + q * 16 + lr;                                        \
        af[q] = *(const s16x8*)&Ap[BUF][ar * 64 + (kb ^ ((ar & 7) << 3))];     \
      }                                                                        \
      _Pragma("unroll") for (int r = 0; r < 2; ++r) {                          \
        int bc = ni * 32 + r * 16 + lr;                                        \
        bg[r] = *(const s16x8*)&Bp[BUF][bc * 64 + (kb ^ ((bc & 7) << 3))];     \
        bu[r] = *(const s16x8*)&Bp[BUF][(bc + 64) * 64 + (kb ^ ((bc & 7) << 3))]; \
      }                                                                        \
      _Pragma("unroll") for (int q = 0; q < 2; ++q)                            \
        _Pragma("unroll") for (int r = 0; r < 2; ++r) {                        \
          accg[q][r] = __builtin_amdgcn_mfma_f32_16x16x32_bf16(af[q], bg[r], accg[q][r], 0, 0, 0); \
          accu[q][r] = __builtin_amdgcn_mfma_f32_16x16x32_bf16(af[q], bu[r], accu[q][r], 0, 0, 0); \
        }                                                                      \
    } }

  f32x4 accg[2][2] = {}, accu[2][2] = {};
  G1_LOAD(A, 0);
  G1_LOAD(B, 1);
  G1_LOAD(C, 2);
  for (int tt = 0; tt < 30; tt += 6) {
    G1_BODY(0, A, tt + 3);
    G1_BODY(1, B, tt + 4);
    G1_BODY(0, C, tt + 5);
    G1_BODY(1, A, tt + 6);
    G1_BODY(0, B, tt + 7);
    G1_BODY(1, C, tt + 8);
  }
  G1_BODY(0, A, 99);   // tile 30
  G1_BODY(1, B, 99);   // tile 31
#undef G1_LOAD
#undef G1_BODY

  // ---- epilogue: stage ter1 rows to LDS, fuse LoRA + silu, store bf16 h ----
  __syncthreads();
  float* tlds = (float*)&Ap[0][0];             // 128 x 16 f32
  for (int idx = tid; idx < 2048; idx += 512) {
    int row = idx >> 4, c = idx & 15;
    int p = list[e * 512 + min(st * 128 + row, n - 1)];
    tlds[idx] = ter1all[(size_t)(p >> 1) * 128 + e * 16 + c];
  }
  __syncthreads();
#pragma unroll
  for (int r = 0; r < 2; ++r) {
    int gc = c0 + ni * 32 + r * 16 + lr;       // global i-col 0..1023
    const float4* g4 = (const float4*)(gupB + ((size_t)e * 2048 + gc) * 16);
    const float4* u4 = (const float4*)(gupB + ((size_t)e * 2048 + 1024 + gc) * 16);
    float gv2[16], uv2[16];
#pragma unroll
    for (int q = 0; q < 4; ++q) {
      float4 gv = g4[q], uv = u4[q];
      gv2[q*4+0]=gv.x; gv2[q*4+1]=gv.y; gv2[q*4+2]=gv.z; gv2[q*4+3]=gv.w;
      uv2[q*4+0]=uv.x; uv2[q*4+1]=uv.y; uv2[q*4+2]=uv.z; uv2[q*4+3]=uv.w;
    }
#pragma unroll
    for (int q = 0; q < 2; ++q) {
#pragma unroll
      for (int j = 0; j < 4; ++j) {
        int row = wr * 32 + q * 16 + lh * 4 + j;
        if (st * 128 + row < n) {
          int p = list[e * 512 + st * 128 + row];
          const float* tv = &tlds[row * 16];
          float dg = 0.f, du = 0.f;
#pragma unroll
          for (int rr = 0; rr < 16; ++rr) { dg += tv[rr] * gv2[rr]; du += tv[rr] * uv2[rr]; }
          float g = accg[q][r][j] + 2.f * dg;
          float u = accu[q][r][j] + 2.f * du;
          h[(size_t)p * 1024 + gc] = f2bf(g / (1.f + __expf(-g)) * u);
        }
      }
    }
  }
}

// ter2[p][r] = h[p] . dlA[e][r], grouped MFMA GEMM (BN=16), split-K=4.
__global__ __launch_bounds__(512) void k_ter2(
    const unsigned short* __restrict__ h, const float* __restrict__ dlA,
    const int* __restrict__ cnt, const int* __restrict__ list,
    float* __restrict__ ter2) {
  int st = blockIdx.x, kcc = blockIdx.y, e = blockIdx.z;
  int n = cnt[e];
  if (st * 128 >= n) return;
  int tid = threadIdx.x;
  __shared__ unsigned short Ap[2][128 * 64];
  __shared__ unsigned short Bp[2][16 * 64];
  const int k0b = kcc * 256;

  const unsigned short* aSrc[2]; int aOff[2];
#pragma unroll
  for (int s = 0; s < 2; ++s) {
    int slot = tid + s * 512;
    int row = slot >> 3, k16 = slot & 7;
    int p = list[e * 512 + min(st * 128 + row, n - 1)];
    aSrc[s] = h + (size_t)p * 1024 + k0b + k16 * 8;
    aOff[s] = row * 64 + ((k16 * 8) ^ ((row & 7) << 3));
  }
  const float* bSrc = nullptr; int bOff = 0;
  if (tid < 128) {
    int r = tid >> 3, kg = tid & 7;
    bSrc = dlA + ((size_t)e * 16 + r) * 1024 + k0b + kg * 8;
    bOff = r * 64 + ((kg * 8) ^ ((r & 7) << 3));
  }
  int lane = tid & 63, wv = tid >> 6;
  int lr = lane & 15, lh = lane >> 4;

  uint4 apre[2]; float4 bpre[2];
#define T2_ISSUE(T) { int kk = (T) * 64;                                   \
    _Pragma("unroll") for (int s = 0; s < 2; ++s)                          \
        apre[s] = *(const uint4*)(aSrc[s] + kk);                           \
    if (tid < 128) { bpre[0] = *(const float4*)(bSrc + kk);                \
                     bpre[1] = *(const float4*)(bSrc + kk + 4); } }

  f32x4 acc = {};
  T2_ISSUE(0);
  for (int t = 0; t < 4; ++t) {
    int buf = t & 1;
#pragma unroll
    for (int s = 0; s < 2; ++s) *(uint4*)&Ap[buf][aOff[s]] = apre[s];
    if (tid < 128) {
      u16x8 o;
      o[0]=f2bf(bpre[0].x); o[1]=f2bf(bpre[0].y); o[2]=f2bf(bpre[0].z); o[3]=f2bf(bpre[0].w);
      o[4]=f2bf(bpre[1].x); o[5]=f2bf(bpre[1].y); o[6]=f2bf(bpre[1].z); o[7]=f2bf(bpre[1].w);
      *(u16x8*)&Bp[buf][bOff] = o;
    }
    __syncthreads();
    if (t < 3) T2_ISSUE(t + 1);
#pragma unroll
    for (int ks = 0; ks < 64; ks += 32) {
      int kb = ks + lh * 8;
      s16x8 b = *(const s16x8*)&Bp[buf][lr * 64 + (kb ^ ((lr & 7) << 3))];
      int ar = wv * 16 + lr;
      s16x8 a = *(const s16x8*)&Ap[buf][ar * 64 + (kb ^ ((ar & 7) << 3))];
      acc = __builtin_amdgcn_mfma_f32_16x16x32_bf16(a, b, acc, 0, 0, 0);
    }
    __syncthreads();
  }
#undef T2_ISSUE
#pragma unroll
  for (int j = 0; j < 4; ++j) {
    int row = wv * 16 + lh * 4 + j;
    if (st * 128 + row < n) {
      int p = list[e * 512 + st * 128 + row];
      atomicAdd(&ter2[p * 16 + lr], acc[j]);
    }
  }
}

// GEMM2: gathered h rows [BM=128] x down[e] [BN=64], full K=1024 (NT=16).
// 3-deep register pipeline. Epilogue fuses down-LoRA, stores per-slot osel.
__global__ __launch_bounds__(512) void k_gemm2(
    const unsigned short* __restrict__ h, const float* __restrict__ down,
    const float* __restrict__ dlB, const float* __restrict__ ter2,
    const int* __restrict__ cnt, const int* __restrict__ list,
    float* __restrict__ osel) {
  const int ct = blockIdx.x;                 // 0..31
  const int st = blockIdx.y;                 // 0..3
  const int e  = blockIdx.z;
  const int n = cnt[e];
  if (st * 128 >= n) return;
  const int tid = threadIdx.x;

  __shared__ unsigned short Ap[2][128 * 64];
  __shared__ unsigned short Bp[2][64 * 64];

  const int c0 = ct * 64;

  const unsigned short *aSrc0, *aSrc1;
  int aOff0, aOff1;
  {
    int row = tid >> 3, k16 = tid & 7;
    int p = list[e * 512 + min(st * 128 + row, n - 1)];
    aSrc0 = h + (size_t)p * 1024 + k16 * 8;
    aOff0 = row * 64 + ((k16 * 8) ^ ((row & 7) << 3));
    int slot = tid + 512;
    row = slot >> 3; k16 = slot & 7;
    p = list[e * 512 + min(st * 128 + row, n - 1)];
    aSrc1 = h + (size_t)p * 1024 + k16 * 8;
    aOff1 = row * 64 + ((k16 * 8) ^ ((row & 7) << 3));
  }
  const int bcol = tid & 63, kg = tid >> 6;  // 8 k-groups of 8
  const float* bSrc = down + (size_t)e * 1024 * 2048 + (size_t)(kg * 8) * 2048 + c0 + bcol;
  const int bOff = bcol * 64 + ((kg * 8) ^ ((bcol & 7) << 3));

  const int lane = tid & 63, wv = tid >> 6;
  const int lr = lane & 15, lh = lane >> 4;
  const int wr = wv >> 1, ni = wv & 1;

  uint4 a0A, a1A, a0B, a1B, a0C, a1C;
  float bA[8], bB[8], bC[8];

#define G2_LOAD(SUF, T) {                                        \
    const int kk = (T) * 64;                                     \
    a0##SUF = *(const uint4*)(aSrc0 + kk);                       \
    a1##SUF = *(const uint4*)(aSrc1 + kk);                       \
    _Pragma("unroll") for (int j = 0; j < 8; ++j)                \
      b##SUF[j] = bSrc[(size_t)(kk + j) * 2048]; }

#define G2_BODY(BUF, SUF, NXT) {                                               \
    *(uint4*)&Ap[BUF][aOff0] = a0##SUF;                                        \
    *(uint4*)&Ap[BUF][aOff1] = a1##SUF;                                        \
    { u16x8 o;                                                                 \
      _Pragma("unroll") for (int j = 0; j < 8; ++j) o[j] = f2bf(b##SUF[j]);    \
      *(u16x8*)&Bp[BUF][bOff] = o; }                                           \
    PIPE_BARRIER();                                                            \
    if ((NXT) < 16) G2_LOAD(SUF, NXT);                                         \
    _Pragma("unroll") for (int ks = 0; ks < 64; ks += 32) {                    \
      int kb = ks + lh * 8;                                                    \
      s16x8 af[2], bd[2];                                                      \
      _Pragma("unroll") for (int q = 0; q < 2; ++q) {                          \
        int ar = wr * 32 + q * 16 + lr;                                        \
        af[q] = *(const s16x8*)&Ap[BUF][ar * 64 + (kb ^ ((ar & 7) << 3))];     \
      }                                                                        \
      _Pragma("unroll") for (int r = 0; r < 2; ++r) {                          \
        int bc = ni * 32 + r * 16 + lr;                                        \
        bd[r] = *(const s16x8*)&Bp[BUF][bc * 64 + (kb ^ ((bc & 7) << 3))];     \
      }                                                                        \
      _Pragma("unroll") for (int q = 0; q < 2; ++q)                            \
        _Pragma("unroll") for (int r = 0; r < 2; ++r)                          \
          acc[q][r] = __builtin_amdgcn_mfma_f32_16x16x32_bf16(af[q], bd[r], acc[q][r], 0, 0, 0); \
    } }

  f32x4 acc[2][2] = {};
  G2_LOAD(A, 0);
  G2_LOAD(B, 1);
  G2_LOAD(C, 2);
  for (int tt = 0; tt < 12; tt += 6) {
    G2_BODY(0, A, tt + 3);
    G2_BODY(1, B, tt + 4);
    G2_BODY(0, C, tt + 5);
    G2_BODY(1, A, tt + 6);
    G2_BODY(0, B, tt + 7);
    G2_BODY(1, C, tt + 8);
  }
  G2_BODY(0, A, 15);   // tile 12, loads tile 15 into set A
  G2_BODY(1, B, 99);   // tile 13
  G2_BODY(0, C, 99);   // tile 14
  G2_BODY(1, A, 99);   // tile 15
#undef G2_LOAD
#undef G2_BODY

  // ---- epilogue: stage ter2 to LDS, fuse down-LoRA, store osel ----
  __syncthreads();
  float* t2l = (float*)&Ap[0][0];            // 128 x 16 f32
  for (int idx = tid; idx < 2048; idx += 512) {
    int row = idx >> 4, c = idx & 15;
    int p = list[e * 512 + min(st * 128 + row, n - 1)];
    t2l[idx] = ter2[p * 16 + c];
  }
  __syncthreads();
#pragma unroll
  for (int r = 0; r < 2; ++r) {
    int yc = c0 + ni * 32 + r * 16 + lr;
    const float4* d4 = (const float4*)(dlB + ((size_t)e * 2048 + yc) * 16);
    float d2[16];
#pragma unroll
    for (int q = 0; q < 4; ++q) {
      float4 v = d4[q];
      d2[q*4+0]=v.x; d2[q*4+1]=v.y; d2[q*4+2]=v.z; d2[q*4+3]=v.w;
    }
#pragma unroll
    for (int q = 0; q < 2; ++q) {
#pragma unroll
      for (int j = 0; j < 4; ++j) {
        int row = wr * 32 + q * 16 + lh * 4 + j;
        if (st * 128 + row < n) {
          int p = list[e * 512 + st * 128 + row];
          const float* tv = &t2l[row * 16];
          float dd = 0.f;
#pragma unroll
          for (int rr = 0; rr < 16; ++rr) dd += tv[rr] * d2[rr];
          osel[(size_t)p * 2048 + yc] = acc[q][r][j] + 2.f * dd;
        }
      }
    }
  }
}

// y[t] = pw[2t]*osel[2t] + pw[2t+1]*osel[2t+1]
__global__ __launch_bounds__(256) void k_comb(
    const float* __restrict__ osel, const float* __restrict__ pw,
    float* __restrict__ y) {
  int i = blockIdx.x * 256 + threadIdx.x;     // float4 index, 262144 total
  int t = i >> 9;
  int c4 = i & 511;
  float w1 = pw[2 * t], w2 = pw[2 * t + 1];
  const float4* o = (const float4*)osel;
  float4 a = o[(size_t)(2 * t) * 512 + c4];
  float4 b = o[(size_t)(2 * t + 1) * 512 + c4];
  float4 rv;
  rv.x = w1 * a.x + w2 * b.x;
  rv.y = w1 * a.y + w2 * b.y;
  rv.z = w1 * a.z + w2 * b.z;
  rv.w = w1 * a.w + w2 * b.w;
  ((float4*)y)[i] = rv;
}

// ---------------------------------------------------------------------------
extern "C" void kernel_launch(void* const* d_in, const int* in_sizes, int n_in,
                              void* d_out, int out_size, void* d_ws, size_t ws_size,
                              hipStream_t stream) {
  (void)in_sizes; (void)n_in; (void)ws_size; (void)out_size;
  const float* x    = (const float*)d_in[0];
  const float* gw   = (const float*)d_in[1];
  const float* gA   = (const float*)d_in[2];
  const float* gB   = (const float*)d_in[3];
  const float* gup  = (const float*)d_in[4];
  const float* down = (const float*)d_in[5];
  const float* gupA = (const float*)d_in[6];
  const float* gupB = (const float*)d_in[7];
  const float* dlA  = (const float*)d_in[8];
  const float* dlB  = (const float*)d_in[9];
  float* y = (float*)d_out;

  char* w = (char*)d_ws;
  int*   cnt           = (int*)(w + OFF_CNT);
  float* ter1all       = (float*)(w + OFF_TER1A);
  float* ter2          = (float*)(w + OFF_TER2);
  int*   list          = (int*)(w + OFF_LIST);
  float* pw            = (float*)(w + OFF_PW);
  float* Wg            = (float*)(w + OFF_WG);
  unsigned short* xbf  = (unsigned short*)(w + OFF_XBF);
  unsigned short* hbuf = (unsigned short*)(w + OFF_H);
  float* osel          = (float*)(w + OFF_OSEL);

  hipMemsetAsync(w, 0, ZERO_SPAN, stream);

  k_gatecomb<<<64, 256, 0, stream>>>(gw, gA, gB, Wg);
  k_router<<<512, 256, 0, stream>>>(x, Wg, cnt, list, pw, xbf);
  k_ter1all<<<dim3(8, 4), 512, 0, stream>>>(xbf, gupA, ter1all);
  k_gemm1<<<dim3(16, 4, 8), 512, 0, stream>>>(xbf, gup, gupB, ter1all, cnt, list, hbuf);
  k_ter2<<<dim3(4, 4, 8), 512, 0, stream>>>(hbuf, dlA, cnt, list, ter2);
  k_gemm2<<<dim3(32, 4, 8), 512, 0, stream>>>(hbuf, down, dlB, ter2, cnt, list, osel);
  k_comb<<<1024, 256, 0, stream>>>(osel, pw, y);
}

// Round 10
// 128.769 us; speedup vs baseline: 1.0749x; 1.0043x over previous
//
#include <hip/hip_runtime.h>

// ---------------------------------------------------------------------------
// MoE gated MLP with LoRA, top-2 of 8, T=512, H=2048, I=1024, R=16.
// Round 10: R9 + (a) XCD-grouped block ids (expert e -> XCD e; A/h panels
// become L2-resident), (b) comb fused into gemm2 epilogue (weighted atomicAdd
// into zeroed y; osel + k_comb deleted). Everything else identical to R9.
// ---------------------------------------------------------------------------

typedef short  s16x8 __attribute__((ext_vector_type(8)));
typedef float  f32x4 __attribute__((ext_vector_type(4)));
typedef unsigned short u16x8 __attribute__((ext_vector_type(8)));

__device__ __forceinline__ unsigned short f2bf(float f) {
  unsigned u = __builtin_bit_cast(unsigned, f);
  u += 0x7fffu + ((u >> 16) & 1u);          // RNE
  return (unsigned short)(u >> 16);
}

// Barrier that does NOT drain vmcnt.
#define PIPE_BARRIER() asm volatile("s_waitcnt lgkmcnt(0)\n\ts_barrier" ::: "memory")

// ---- workspace layout (bytes). [0, ZERO_SPAN) memset to 0 each launch ----
#define OFF_CNT    0u          // 8 int (pad 256)
#define OFF_TER1A  256u        // 512*128 f32 = 262144
#define OFF_TER2   262400u     // 1024*16 f32 = 65536
#define ZERO_SPAN  327936u
#define OFF_LIST   327936u     // 8*512 int = 16384
#define OFF_PW     344320u     // 1024 f32 = 4096
#define OFF_WG     348416u     // 8*2048 f32 = 65536
#define OFF_XBF    413952u     // 512*2048 bf16 = 2097152
#define OFF_H      2511104u    // 1024*1024 bf16 = 2097152
// total ~4.6 MB

// ---------------------------------------------------------------------------
__global__ void k_gatecomb(const float* __restrict__ gw, const float* __restrict__ gA,
                           const float* __restrict__ gB, float* __restrict__ Wg) {
  int idx = blockIdx.x * 256 + threadIdx.x;   // 16384
  int e = idx >> 11, h = idx & 2047;
  float acc = gw[idx];
#pragma unroll
  for (int r = 0; r < 16; ++r)
    acc += 2.0f * gB[e * 16 + r] * gA[r * 2048 + h];
  Wg[idx] = acc;
}

// fp32 router (exact logits -> identical top-k to reference) + fused x->bf16.
__global__ void k_router(const float* __restrict__ x, const float* __restrict__ Wg,
                         int* __restrict__ cnt, int* __restrict__ list,
                         float* __restrict__ pw, unsigned short* __restrict__ xbf) {
  int t = blockIdx.x, tid = threadIdx.x;
  __shared__ float xs[2048];
  __shared__ float logits[8];
  for (int i = tid; i < 2048; i += 256) xs[i] = x[(size_t)t * 2048 + i];
  __syncthreads();
  {
    u16x8 o;
#pragma unroll
    for (int j = 0; j < 8; ++j) o[j] = f2bf(xs[tid * 8 + j]);
    *(u16x8*)(xbf + (size_t)t * 2048 + tid * 8) = o;
  }
  int e = tid >> 5, l = tid & 31;
  float s = 0.f;
  for (int h = l; h < 2048; h += 32) s += xs[h] * Wg[e * 2048 + h];
#pragma unroll
  for (int off = 16; off >= 1; off >>= 1) s += __shfl_down(s, off, 32);
  if (l == 0) logits[e] = s;
  __syncthreads();
  if (tid == 0) {
    float m = logits[0];
#pragma unroll
    for (int i = 1; i < 8; ++i) m = fmaxf(m, logits[i]);
    float ex[8];
#pragma unroll
    for (int i = 0; i < 8; ++i) ex[i] = __expf(logits[i] - m);
    int e1 = 0; float v1 = ex[0];
#pragma unroll
    for (int i = 1; i < 8; ++i) if (ex[i] > v1) { v1 = ex[i]; e1 = i; }
    int e2 = -1; float v2 = -1.f;
#pragma unroll
    for (int i = 0; i < 8; ++i) if (i != e1 && ex[i] > v2) { v2 = ex[i]; e2 = i; }
    float inv = 1.f / (v1 + v2);
    int p1 = 2 * t, p2 = 2 * t + 1;
    pw[p1] = v1 * inv;
    pw[p2] = v2 * inv;
    int s1 = atomicAdd(&cnt[e1], 1); list[e1 * 512 + s1] = p1;
    int s2 = atomicAdd(&cnt[e2], 1); list[e2 * 512 + s2] = p2;
  }
}

// ter1all[t][er] = x[t] . gupA_flat[er]  (er = e*16+r). Round-2-proven.
__global__ __launch_bounds__(512) void k_ter1all(
    const unsigned short* __restrict__ xbf, const float* __restrict__ gupA,
    float* __restrict__ ter1all) {
  int trow = blockIdx.x, kcc = blockIdx.y;
  int tid = threadIdx.x;
  __shared__ unsigned short Ap[2][64 * 64];
  __shared__ unsigned short Bp[2][128 * 64];
  const int k0b = kcc * 512;

  int rowA = tid >> 3, k16A = tid & 7;
  const unsigned short* aSrc = xbf + (size_t)(trow * 64 + rowA) * 2048 + k0b + k16A * 8;
  int aOff = rowA * 64 + ((k16A * 8) ^ ((rowA & 7) << 3));

  const float* bSrc[2]; int bOff[2];
#pragma unroll
  for (int s = 0; s < 2; ++s) {
    int slot = tid + s * 512;
    int er = slot >> 3, kg = slot & 7;
    bSrc[s] = gupA + (size_t)er * 2048 + k0b + kg * 8;
    bOff[s] = er * 64 + ((kg * 8) ^ ((er & 7) << 3));
  }
  int lane = tid & 63, wv = tid >> 6;
  int lr = lane & 15, lh = lane >> 4;

  uint4 apre; float4 bpre[2][2];
#define TA_ISSUE(T) { int kk = (T) * 64;                                   \
    apre = *(const uint4*)(aSrc + kk);                                     \
    _Pragma("unroll") for (int s = 0; s < 2; ++s) {                        \
      bpre[s][0] = *(const float4*)(bSrc[s] + kk);                         \
      bpre[s][1] = *(const float4*)(bSrc[s] + kk + 4); } }

  f32x4 acc[4] = {};
  TA_ISSUE(0);
  for (int t = 0; t < 8; ++t) {
    int buf = t & 1;
    *(uint4*)&Ap[buf][aOff] = apre;
#pragma unroll
    for (int s = 0; s < 2; ++s) {
      u16x8 o;
      o[0]=f2bf(bpre[s][0].x); o[1]=f2bf(bpre[s][0].y); o[2]=f2bf(bpre[s][0].z); o[3]=f2bf(bpre[s][0].w);
      o[4]=f2bf(bpre[s][1].x); o[5]=f2bf(bpre[s][1].y); o[6]=f2bf(bpre[s][1].z); o[7]=f2bf(bpre[s][1].w);
      *(u16x8*)&Bp[buf][bOff[s]] = o;
    }
    __syncthreads();
    if (t < 7) TA_ISSUE(t + 1);
#pragma unroll
    for (int ks = 0; ks < 64; ks += 32) {
      int kb = ks + lh * 8;
      int bc = wv * 16 + lr;
      s16x8 b = *(const s16x8*)&Bp[buf][bc * 64 + (kb ^ ((bc & 7) << 3))];
#pragma unroll
      for (int fr = 0; fr < 4; ++fr) {
        int ar = fr * 16 + lr;
        s16x8 a = *(const s16x8*)&Ap[buf][ar * 64 + (kb ^ ((ar & 7) << 3))];
        acc[fr] = __builtin_amdgcn_mfma_f32_16x16x32_bf16(a, b, acc[fr], 0, 0, 0);
      }
    }
    __syncthreads();
  }
#undef TA_ISSUE
#pragma unroll
  for (int fr = 0; fr < 4; ++fr)
#pragma unroll
    for (int j = 0; j < 4; ++j) {
      int tok = trow * 64 + fr * 16 + lh * 4 + j;
      atomicAdd(&ter1all[tok * 128 + wv * 16 + lr], acc[fr][j]);
    }
}

// ---------------------------------------------------------------------------
// GEMM1: gathered x rows [BM=128] x gup[e], B-tile = 64 gate + 64 up cols,
// full K=2048 (NT=32). 3-deep register pipeline. id = e + 8*(ct + 16*st):
// expert e -> XCD e so the shared A-panel stays L2-resident.
__global__ __launch_bounds__(512) void k_gemm1(
    const unsigned short* __restrict__ xbf, const float* __restrict__ gup,
    const float* __restrict__ gupB, const float* __restrict__ ter1all,
    const int* __restrict__ cnt, const int* __restrict__ list,
    unsigned short* __restrict__ h) {
  const int id = blockIdx.x;                 // 0..511
  const int e  = id & 7;
  const int m  = id >> 3;
  const int ct = m & 15;                     // i-cols [ct*64, ct*64+64)
  const int st = m >> 4;                     // 0..3
  const int n = cnt[e];
  if (st * 128 >= n) return;
  const int tid = threadIdx.x;

  __shared__ unsigned short Ap[2][128 * 64];   // [row][k] swizzled
  __shared__ unsigned short Bp[2][128 * 64];   // [col][k]: 0..63 gate, 64..127 up

  const int c0 = ct * 64;

  const unsigned short *aSrc0, *aSrc1;
  int aOff0, aOff1;
  {
    int row = tid >> 3, k16 = tid & 7;
    int p = list[e * 512 + min(st * 128 + row, n - 1)];
    aSrc0 = xbf + (size_t)(p >> 1) * 2048 + k16 * 8;
    aOff0 = row * 64 + ((k16 * 8) ^ ((row & 7) << 3));
    int slot = tid + 512;
    row = slot >> 3; k16 = slot & 7;
    p = list[e * 512 + min(st * 128 + row, n - 1)];
    aSrc1 = xbf + (size_t)(p >> 1) * 2048 + k16 * 8;
    aOff1 = row * 64 + ((k16 * 8) ^ ((row & 7) << 3));
  }
  // B: col 0..127; global col = gate c0+col (col<64) else up 1024+c0+col-64
  const int bcol = tid & 127, kgrp = tid >> 7;   // 4 k-groups of 16
  const int gcg = (bcol < 64) ? (c0 + bcol) : (1024 + c0 + bcol - 64);
  const float* bSrc = gup + (size_t)e * 2048 * 2048 + (size_t)(kgrp * 16) * 2048 + gcg;
  const int sw = (bcol & 7) << 3;
  const int bOff0 = bcol * 64 + ((kgrp * 16) ^ sw);
  const int bOff1 = bcol * 64 + ((kgrp * 16 + 8) ^ sw);

  const int lane = tid & 63, wv = tid >> 6;
  const int lr = lane & 15, lh = lane >> 4;
  const int wr = wv >> 1, ni = wv & 1;       // 4 M-waves x 2 N-waves

  uint4 a0A, a1A, a0B, a1B, a0C, a1C;
  float bA[16], bB[16], bC[16];

#define G1_LOAD(SUF, T) {                                        \
    const int kk = (T) * 64;                                     \
    a0##SUF = *(const uint4*)(aSrc0 + kk);                       \
    a1##SUF = *(const uint4*)(aSrc1 + kk);                       \
    _Pragma("unroll") for (int j = 0; j < 16; ++j)               \
      b##SUF[j] = bSrc[(size_t)(kk + j) * 2048]; }

#define G1_BODY(BUF, SUF, NXT) {                                               \
    *(uint4*)&Ap[BUF][aOff0] = a0##SUF;                                        \
    *(uint4*)&Ap[BUF][aOff1] = a1##SUF;                                        \
    { u16x8 o0, o1;                                                            \
      _Pragma("unroll") for (int j = 0; j < 8; ++j) {                          \
        o0[j] = f2bf(b##SUF[j]); o1[j] = f2bf(b##SUF[j + 8]); }                \
      *(u16x8*)&Bp[BUF][bOff0] = o0;                                           \
      *(u16x8*)&Bp[BUF][bOff1] = o1; }                                         \
    PIPE_BARRIER();                                                            \
    if ((NXT) < 32) G1_LOAD(SUF, NXT);                                         \
    _Pragma("unroll") for (int ks = 0; ks < 64; ks += 32) {                    \
      int kb = ks + lh * 8;                                                    \
      s16x8 af[2], bg[2], bu[2];                                               \
      _Pragma("unroll") for (int q = 0; q < 2; ++q) {                          \
        int ar = wr * 32 + q * 16 + lr;                                        \
        af[q] = *(const s16x8*)&Ap[BUF][ar * 64 + (kb ^ ((ar & 7) << 3))];     \
      }                                                                        \
      _Pragma("unroll") for (int r = 0; r < 2; ++r) {                          \
        int bc = ni * 32 + r * 16 + lr;                                        \
        bg[r] = *(const s16x8*)&Bp[BUF][bc * 64 + (kb ^ ((bc & 7) << 3))];     \
        bu[r] = *(const s16x8*)&Bp[BUF][(bc + 64) * 64 + (kb ^ ((bc & 7) << 3))]; \
      }                                                                        \
      _Pragma("unroll") for (int q = 0; q < 2; ++q)                            \
        _Pragma("unroll") for (int r = 0; r < 2; ++r) {                        \
          accg[q][r] = __builtin_amdgcn_mfma_f32_16x16x32_bf16(af[q], bg[r], accg[q][r], 0, 0, 0); \
          accu[q][r] = __builtin_amdgcn_mfma_f32_16x16x32_bf16(af[q], bu[r], accu[q][r], 0, 0, 0); \
        }                                                                      \
    } }

  f32x4 accg[2][2] = {}, accu[2][2] = {};
  G1_LOAD(A, 0);
  G1_LOAD(B, 1);
  G1_LOAD(C, 2);
  for (int tt = 0; tt < 30; tt += 6) {
    G1_BODY(0, A, tt + 3);
    G1_BODY(1, B, tt + 4);
    G1_BODY(0, C, tt + 5);
    G1_BODY(1, A, tt + 6);
    G1_BODY(0, B, tt + 7);
    G1_BODY(1, C, tt + 8);
  }
  G1_BODY(0, A, 99);   // tile 30
  G1_BODY(1, B, 99);   // tile 31
#undef G1_LOAD
#undef G1_BODY

  // ---- epilogue: stage ter1 rows to LDS, fuse LoRA + silu, store bf16 h ----
  __syncthreads();
  float* tlds = (float*)&Ap[0][0];             // 128 x 16 f32
  for (int idx = tid; idx < 2048; idx += 512) {
    int row = idx >> 4, c = idx & 15;
    int p = list[e * 512 + min(st * 128 + row, n - 1)];
    tlds[idx] = ter1all[(size_t)(p >> 1) * 128 + e * 16 + c];
  }
  __syncthreads();
#pragma unroll
  for (int r = 0; r < 2; ++r) {
    int gc = c0 + ni * 32 + r * 16 + lr;       // global i-col 0..1023
    const float4* g4 = (const float4*)(gupB + ((size_t)e * 2048 + gc) * 16);
    const float4* u4 = (const float4*)(gupB + ((size_t)e * 2048 + 1024 + gc) * 16);
    float gv2[16], uv2[16];
#pragma unroll
    for (int q = 0; q < 4; ++q) {
      float4 gv = g4[q], uv = u4[q];
      gv2[q*4+0]=gv.x; gv2[q*4+1]=gv.y; gv2[q*4+2]=gv.z; gv2[q*4+3]=gv.w;
      uv2[q*4+0]=uv.x; uv2[q*4+1]=uv.y; uv2[q*4+2]=uv.z; uv2[q*4+3]=uv.w;
    }
#pragma unroll
    for (int q = 0; q < 2; ++q) {
#pragma unroll
      for (int j = 0; j < 4; ++j) {
        int row = wr * 32 + q * 16 + lh * 4 + j;
        if (st * 128 + row < n) {
          int p = list[e * 512 + st * 128 + row];
          const float* tv = &tlds[row * 16];
          float dg = 0.f, du = 0.f;
#pragma unroll
          for (int rr = 0; rr < 16; ++rr) { dg += tv[rr] * gv2[rr]; du += tv[rr] * uv2[rr]; }
          float g = accg[q][r][j] + 2.f * dg;
          float u = accu[q][r][j] + 2.f * du;
          h[(size_t)p * 1024 + gc] = f2bf(g / (1.f + __expf(-g)) * u);
        }
      }
    }
  }
}

// ter2[p][r] = h[p] . dlA[e][r], grouped MFMA GEMM (BN=16), split-K=4.
__global__ __launch_bounds__(512) void k_ter2(
    const unsigned short* __restrict__ h, const float* __restrict__ dlA,
    const int* __restrict__ cnt, const int* __restrict__ list,
    float* __restrict__ ter2) {
  int st = blockIdx.x, kcc = blockIdx.y, e = blockIdx.z;
  int n = cnt[e];
  if (st * 128 >= n) return;
  int tid = threadIdx.x;
  __shared__ unsigned short Ap[2][128 * 64];
  __shared__ unsigned short Bp[2][16 * 64];
  const int k0b = kcc * 256;

  const unsigned short* aSrc[2]; int aOff[2];
#pragma unroll
  for (int s = 0; s < 2; ++s) {
    int slot = tid + s * 512;
    int row = slot >> 3, k16 = slot & 7;
    int p = list[e * 512 + min(st * 128 + row, n - 1)];
    aSrc[s] = h + (size_t)p * 1024 + k0b + k16 * 8;
    aOff[s] = row * 64 + ((k16 * 8) ^ ((row & 7) << 3));
  }
  const float* bSrc = nullptr; int bOff = 0;
  if (tid < 128) {
    int r = tid >> 3, kg = tid & 7;
    bSrc = dlA + ((size_t)e * 16 + r) * 1024 + k0b + kg * 8;
    bOff = r * 64 + ((kg * 8) ^ ((r & 7) << 3));
  }
  int lane = tid & 63, wv = tid >> 6;
  int lr = lane & 15, lh = lane >> 4;

  uint4 apre[2]; float4 bpre[2];
#define T2_ISSUE(T) { int kk = (T) * 64;                                   \
    _Pragma("unroll") for (int s = 0; s < 2; ++s)                          \
        apre[s] = *(const uint4*)(aSrc[s] + kk);                           \
    if (tid < 128) { bpre[0] = *(const float4*)(bSrc + kk);                \
                     bpre[1] = *(const float4*)(bSrc + kk + 4); } }

  f32x4 acc = {};
  T2_ISSUE(0);
  for (int t = 0; t < 4; ++t) {
    int buf = t & 1;
#pragma unroll
    for (int s = 0; s < 2; ++s) *(uint4*)&Ap[buf][aOff[s]] = apre[s];
    if (tid < 128) {
      u16x8 o;
      o[0]=f2bf(bpre[0].x); o[1]=f2bf(bpre[0].y); o[2]=f2bf(bpre[0].z); o[3]=f2bf(bpre[0].w);
      o[4]=f2bf(bpre[1].x); o[5]=f2bf(bpre[1].y); o[6]=f2bf(bpre[1].z); o[7]=f2bf(bpre[1].w);
      *(u16x8*)&Bp[buf][bOff] = o;
    }
    __syncthreads();
    if (t < 3) T2_ISSUE(t + 1);
#pragma unroll
    for (int ks = 0; ks < 64; ks += 32) {
      int kb = ks + lh * 8;
      s16x8 b = *(const s16x8*)&Bp[buf][lr * 64 + (kb ^ ((lr & 7) << 3))];
      int ar = wv * 16 + lr;
      s16x8 a = *(const s16x8*)&Ap[buf][ar * 64 + (kb ^ ((ar & 7) << 3))];
      acc = __builtin_amdgcn_mfma_f32_16x16x32_bf16(a, b, acc, 0, 0, 0);
    }
    __syncthreads();
  }
#undef T2_ISSUE
#pragma unroll
  for (int j = 0; j < 4; ++j) {
    int row = wv * 16 + lh * 4 + j;
    if (st * 128 + row < n) {
      int p = list[e * 512 + st * 128 + row];
      atomicAdd(&ter2[p * 16 + lr], acc[j]);
    }
  }
}

// GEMM2: gathered h rows [BM=128] x down[e] [BN=64], full K=1024 (NT=16).
// 3-deep register pipeline. id = e + 8*(ct + 32*st): expert -> XCD.
// Epilogue fuses down-LoRA + routing weight; atomicAdd into zeroed y.
__global__ __launch_bounds__(512) void k_gemm2(
    const unsigned short* __restrict__ h, const float* __restrict__ down,
    const float* __restrict__ dlB, const float* __restrict__ ter2,
    const int* __restrict__ cnt, const int* __restrict__ list,
    const float* __restrict__ pw, float* __restrict__ y) {
  const int id = blockIdx.x;                 // 0..1023
  const int e  = id & 7;
  const int m  = id >> 3;
  const int ct = m & 31;                     // 0..31
  const int st = m >> 5;                     // 0..3
  const int n = cnt[e];
  if (st * 128 >= n) return;
  const int tid = threadIdx.x;

  __shared__ unsigned short Ap[2][128 * 64];
  __shared__ unsigned short Bp[2][64 * 64];

  const int c0 = ct * 64;

  const unsigned short *aSrc0, *aSrc1;
  int aOff0, aOff1;
  {
    int row = tid >> 3, k16 = tid & 7;
    int p = list[e * 512 + min(st * 128 + row, n - 1)];
    aSrc0 = h + (size_t)p * 1024 + k16 * 8;
    aOff0 = row * 64 + ((k16 * 8) ^ ((row & 7) << 3));
    int slot = tid + 512;
    row = slot >> 3; k16 = slot & 7;
    p = list[e * 512 + min(st * 128 + row, n - 1)];
    aSrc1 = h + (size_t)p * 1024 + k16 * 8;
    aOff1 = row * 64 + ((k16 * 8) ^ ((row & 7) << 3));
  }
  const int bcol = tid & 63, kg = tid >> 6;  // 8 k-groups of 8
  const float* bSrc = down + (size_t)e * 1024 * 2048 + (size_t)(kg * 8) * 2048 + c0 + bcol;
  const int bOff = bcol * 64 + ((kg * 8) ^ ((bcol & 7) << 3));

  const int lane = tid & 63, wv = tid >> 6;
  const int lr = lane & 15, lh = lane >> 4;
  const int wr = wv >> 1, ni = wv & 1;

  uint4 a0A, a1A, a0B, a1B, a0C, a1C;
  float bA[8], bB[8], bC[8];

#define G2_LOAD(SUF, T) {                                        \
    const int kk = (T) * 64;                                     \
    a0##SUF = *(const uint4*)(aSrc0 + kk);                       \
    a1##SUF = *(const uint4*)(aSrc1 + kk);                       \
    _Pragma("unroll") for (int j = 0; j < 8; ++j)                \
      b##SUF[j] = bSrc[(size_t)(kk + j) * 2048]; }

#define G2_BODY(BUF, SUF, NXT) {                                               \
    *(uint4*)&Ap[BUF][aOff0] = a0##SUF;                                        \
    *(uint4*)&Ap[BUF][aOff1] = a1##SUF;                                        \
    { u16x8 o;                                                                 \
      _Pragma("unroll") for (int j = 0; j < 8; ++j) o[j] = f2bf(b##SUF[j]);    \
      *(u16x8*)&Bp[BUF][bOff] = o; }                                           \
    PIPE_BARRIER();                                                            \
    if ((NXT) < 16) G2_LOAD(SUF, NXT);                                         \
    _Pragma("unroll") for (int ks = 0; ks < 64; ks += 32) {                    \
      int kb = ks + lh * 8;                                                    \
      s16x8 af[2], bd[2];                                                      \
      _Pragma("unroll") for (int q = 0; q < 2; ++q) {                          \
        int ar = wr * 32 + q * 16 + lr;                                        \
        af[q] = *(const s16x8*)&Ap[BUF][ar * 64 + (kb ^ ((ar & 7) << 3))];     \
      }                                                                        \
      _Pragma("unroll") for (int r = 0; r < 2; ++r) {                          \
        int bc = ni * 32 + r * 16 + lr;                                        \
        bd[r] = *(const s16x8*)&Bp[BUF][bc * 64 + (kb ^ ((bc & 7) << 3))];     \
      }                                                                        \
      _Pragma("unroll") for (int q = 0; q < 2; ++q)                            \
        _Pragma("unroll") for (int r = 0; r < 2; ++r)                          \
          acc[q][r] = __builtin_amdgcn_mfma_f32_16x16x32_bf16(af[q], bd[r], acc[q][r], 0, 0, 0); \
    } }

  f32x4 acc[2][2] = {};
  G2_LOAD(A, 0);
  G2_LOAD(B, 1);
  G2_LOAD(C, 2);
  for (int tt = 0; tt < 12; tt += 6) {
    G2_BODY(0, A, tt + 3);
    G2_BODY(1, B, tt + 4);
    G2_BODY(0, C, tt + 5);
    G2_BODY(1, A, tt + 6);
    G2_BODY(0, B, tt + 7);
    G2_BODY(1, C, tt + 8);
  }
  G2_BODY(0, A, 15);   // tile 12, loads tile 15 into set A
  G2_BODY(1, B, 99);   // tile 13
  G2_BODY(0, C, 99);   // tile 14
  G2_BODY(1, A, 99);   // tile 15
#undef G2_LOAD
#undef G2_BODY

  // ---- epilogue: stage ter2 to LDS, fuse down-LoRA + weight, add into y ----
  __syncthreads();
  float* t2l = (float*)&Ap[0][0];            // 128 x 16 f32
  for (int idx = tid; idx < 2048; idx += 512) {
    int row = idx >> 4, c = idx & 15;
    int p = list[e * 512 + min(st * 128 + row, n - 1)];
    t2l[idx] = ter2[p * 16 + c];
  }
  __syncthreads();
#pragma unroll
  for (int r = 0; r < 2; ++r) {
    int yc = c0 + ni * 32 + r * 16 + lr;
    const float4* d4 = (const float4*)(dlB + ((size_t)e * 2048 + yc) * 16);
    float d2[16];
#pragma unroll
    for (int q = 0; q < 4; ++q) {
      float4 v = d4[q];
      d2[q*4+0]=v.x; d2[q*4+1]=v.y; d2[q*4+2]=v.z; d2[q*4+3]=v.w;
    }
#pragma unroll
    for (int q = 0; q < 2; ++q) {
#pragma unroll
      for (int j = 0; j < 4; ++j) {
        int row = wr * 32 + q * 16 + lh * 4 + j;
        if (st * 128 + row < n) {
          int p = list[e * 512 + st * 128 + row];
          const float* tv = &t2l[row * 16];
          float dd = 0.f;
#pragma unroll
          for (int rr = 0; rr < 16; ++rr) dd += tv[rr] * d2[rr];
          atomicAdd(&y[(size_t)(p >> 1) * 2048 + yc],
                    pw[p] * (acc[q][r][j] + 2.f * dd));
        }
      }
    }
  }
}

// ---------------------------------------------------------------------------
extern "C" void kernel_launch(void* const* d_in, const int* in_sizes, int n_in,
                              void* d_out, int out_size, void* d_ws, size_t ws_size,
                              hipStream_t stream) {
  (void)in_sizes; (void)n_in; (void)ws_size;
  const float* x    = (const float*)d_in[0];
  const float* gw   = (const float*)d_in[1];
  const float* gA   = (const float*)d_in[2];
  const float* gB   = (const float*)d_in[3];
  const float* gup  = (const float*)d_in[4];
  const float* down = (const float*)d_in[5];
  const float* gupA = (const float*)d_in[6];
  const float* gupB = (const float*)d_in[7];
  const float* dlA  = (const float*)d_in[8];
  const float* dlB  = (const float*)d_in[9];
  float* y = (float*)d_out;

  char* w = (char*)d_ws;
  int*   cnt           = (int*)(w + OFF_CNT);
  float* ter1all       = (float*)(w + OFF_TER1A);
  float* ter2          = (float*)(w + OFF_TER2);
  int*   list          = (int*)(w + OFF_LIST);
  float* pw            = (float*)(w + OFF_PW);
  float* Wg            = (float*)(w + OFF_WG);
  unsigned short* xbf  = (unsigned short*)(w + OFF_XBF);
  unsigned short* hbuf = (unsigned short*)(w + OFF_H);

  hipMemsetAsync(w, 0, ZERO_SPAN, stream);
  hipMemsetAsync(y, 0, (size_t)out_size * sizeof(float), stream);

  k_gatecomb<<<64, 256, 0, stream>>>(gw, gA, gB, Wg);
  k_router<<<512, 256, 0, stream>>>(x, Wg, cnt, list, pw, xbf);
  k_ter1all<<<dim3(8, 4), 512, 0, stream>>>(xbf, gupA, ter1all);
  k_gemm1<<<512, 512, 0, stream>>>(xbf, gup, gupB, ter1all, cnt, list, hbuf);
  k_ter2<<<dim3(4, 4, 8), 512, 0, stream>>>(hbuf, dlA, cnt, list, ter2);
  k_gemm2<<<1024, 512, 0, stream>>>(hbuf, down, dlB, ter2, cnt, list, pw, y);
}

// Round 11
// 124.496 us; speedup vs baseline: 1.1118x; 1.0343x over previous
//
#include <hip/hip_runtime.h>

// ---------------------------------------------------------------------------
// MoE gated MLP with LoRA, top-2 of 8, T=512, H=2048, I=1024, R=16.
// Round 11: LoRA-A projections fused INTO the main GEMM K-loops (both cover
// full K per block): gemm1 computes ter1 (x . gupA) and gemm2 computes ter2
// (h . dlA) as +2 MFMA/body with a small staged 16-col B2 tile. k_ter1all and
// k_ter2 kernels deleted; chain is memsets -> gatecomb -> router -> gemm1 ->
// gemm2. K-loop/pipeline/staging otherwise identical to round 10.
// ---------------------------------------------------------------------------

typedef short  s16x8 __attribute__((ext_vector_type(8)));
typedef float  f32x4 __attribute__((ext_vector_type(4)));
typedef unsigned short u16x8 __attribute__((ext_vector_type(8)));

__device__ __forceinline__ unsigned short f2bf(float f) {
  unsigned u = __builtin_bit_cast(unsigned, f);
  u += 0x7fffu + ((u >> 16) & 1u);          // RNE
  return (unsigned short)(u >> 16);
}

// Barrier that does NOT drain vmcnt.
#define PIPE_BARRIER() asm volatile("s_waitcnt lgkmcnt(0)\n\ts_barrier" ::: "memory")

// ---- workspace layout (bytes). [0, ZERO_SPAN) memset to 0 each launch ----
#define OFF_CNT    0u          // 8 int (pad 256)
#define ZERO_SPAN  256u
#define OFF_LIST   256u        // 8*512 int = 16384
#define OFF_PW     16640u      // 1024 f32 = 4096
#define OFF_WG     20736u      // 8*2048 f32 = 65536
#define OFF_XBF    86272u      // 512*2048 bf16 = 2097152
#define OFF_H      2183424u    // 1024*1024 bf16 = 2097152
// total ~4.3 MB

// ---------------------------------------------------------------------------
__global__ void k_gatecomb(const float* __restrict__ gw, const float* __restrict__ gA,
                           const float* __restrict__ gB, float* __restrict__ Wg) {
  int idx = blockIdx.x * 256 + threadIdx.x;   // 16384
  int e = idx >> 11, h = idx & 2047;
  float acc = gw[idx];
#pragma unroll
  for (int r = 0; r < 16; ++r)
    acc += 2.0f * gB[e * 16 + r] * gA[r * 2048 + h];
  Wg[idx] = acc;
}

// fp32 router (exact logits -> identical top-k to reference) + fused x->bf16.
__global__ void k_router(const float* __restrict__ x, const float* __restrict__ Wg,
                         int* __restrict__ cnt, int* __restrict__ list,
                         float* __restrict__ pw, unsigned short* __restrict__ xbf) {
  int t = blockIdx.x, tid = threadIdx.x;
  __shared__ float xs[2048];
  __shared__ float logits[8];
  for (int i = tid; i < 2048; i += 256) xs[i] = x[(size_t)t * 2048 + i];
  __syncthreads();
  {
    u16x8 o;
#pragma unroll
    for (int j = 0; j < 8; ++j) o[j] = f2bf(xs[tid * 8 + j]);
    *(u16x8*)(xbf + (size_t)t * 2048 + tid * 8) = o;
  }
  int e = tid >> 5, l = tid & 31;
  float s = 0.f;
  for (int h = l; h < 2048; h += 32) s += xs[h] * Wg[e * 2048 + h];
#pragma unroll
  for (int off = 16; off >= 1; off >>= 1) s += __shfl_down(s, off, 32);
  if (l == 0) logits[e] = s;
  __syncthreads();
  if (tid == 0) {
    float m = logits[0];
#pragma unroll
    for (int i = 1; i < 8; ++i) m = fmaxf(m, logits[i]);
    float ex[8];
#pragma unroll
    for (int i = 0; i < 8; ++i) ex[i] = __expf(logits[i] - m);
    int e1 = 0; float v1 = ex[0];
#pragma unroll
    for (int i = 1; i < 8; ++i) if (ex[i] > v1) { v1 = ex[i]; e1 = i; }
    int e2 = -1; float v2 = -1.f;
#pragma unroll
    for (int i = 0; i < 8; ++i) if (i != e1 && ex[i] > v2) { v2 = ex[i]; e2 = i; }
    float inv = 1.f / (v1 + v2);
    int p1 = 2 * t, p2 = 2 * t + 1;
    pw[p1] = v1 * inv;
    pw[p2] = v2 * inv;
    int s1 = atomicAdd(&cnt[e1], 1); list[e1 * 512 + s1] = p1;
    int s2 = atomicAdd(&cnt[e2], 1); list[e2 * 512 + s2] = p2;
  }
}

// ---------------------------------------------------------------------------
// GEMM1: gathered x rows [BM=128] x gup[e] (64 gate + 64 up cols), full
// K=2048 (NT=32), 3-deep register pipeline. FUSED: ter1 = x . gupA[e] as +2
// MFMA/body with a 16x64 gupA sub-tile (Bp2). Epilogue: silu(g+2dg)*(u+2du).
__global__ __launch_bounds__(512) void k_gemm1(
    const unsigned short* __restrict__ xbf, const float* __restrict__ gup,
    const float* __restrict__ gupA, const float* __restrict__ gupB,
    const int* __restrict__ cnt, const int* __restrict__ list,
    unsigned short* __restrict__ h) {
  const int id = blockIdx.x;                 // 0..511
  const int e  = id & 7;
  const int m  = id >> 3;
  const int ct = m & 15;                     // i-cols [ct*64, ct*64+64)
  const int st = m >> 4;                     // 0..3
  const int n = cnt[e];
  if (st * 128 >= n) return;
  const int tid = threadIdx.x;

  __shared__ unsigned short Ap[2][128 * 64];   // [row][k] swizzled
  __shared__ unsigned short Bp[2][128 * 64];   // [col][k]: 0..63 gate, 64..127 up
  __shared__ unsigned short Bp2[2][16 * 64];   // gupA [r][k]

  const int c0 = ct * 64;

  const unsigned short *aSrc0, *aSrc1;
  int aOff0, aOff1;
  {
    int row = tid >> 3, k16 = tid & 7;
    int p = list[e * 512 + min(st * 128 + row, n - 1)];
    aSrc0 = xbf + (size_t)(p >> 1) * 2048 + k16 * 8;
    aOff0 = row * 64 + ((k16 * 8) ^ ((row & 7) << 3));
    int slot = tid + 512;
    row = slot >> 3; k16 = slot & 7;
    p = list[e * 512 + min(st * 128 + row, n - 1)];
    aSrc1 = xbf + (size_t)(p >> 1) * 2048 + k16 * 8;
    aOff1 = row * 64 + ((k16 * 8) ^ ((row & 7) << 3));
  }
  // B: col 0..127; global col = gate c0+col (col<64) else up 1024+c0+col-64
  const int bcol = tid & 127, kgrp = tid >> 7;   // 4 k-groups of 16
  const int gcg = (bcol < 64) ? (c0 + bcol) : (1024 + c0 + bcol - 64);
  const float* bSrc = gup + (size_t)e * 2048 * 2048 + (size_t)(kgrp * 16) * 2048 + gcg;
  const int sw = (bcol & 7) << 3;
  const int bOff0 = bcol * 64 + ((kgrp * 16) ^ sw);
  const int bOff1 = bcol * 64 + ((kgrp * 16 + 8) ^ sw);

  // gupA sub-tile staging (threads 0..127): 16 r x 8 k-chunks
  const int gr = (tid >> 3) & 15, gk = tid & 7;
  const float* gaSrc = gupA + ((size_t)e * 16 + gr) * 2048 + gk * 8;
  const int gaOff = gr * 64 + ((gk * 8) ^ ((gr & 7) << 3));

  const int lane = tid & 63, wv = tid >> 6;
  const int lr = lane & 15, lh = lane >> 4;
  const int wr = wv >> 1, ni = wv & 1;       // 4 M-waves x 2 N-waves

  uint4 a0A, a1A, a0B, a1B, a0C, a1C;
  float bA[16], bB[16], bC[16];
  float4 g0A, g1A, g0B, g1B, g0C, g1C;

#define G1_LOAD(SUF, T) {                                        \
    const int kk = (T) * 64;                                     \
    a0##SUF = *(const uint4*)(aSrc0 + kk);                       \
    a1##SUF = *(const uint4*)(aSrc1 + kk);                       \
    _Pragma("unroll") for (int j = 0; j < 16; ++j)               \
      b##SUF[j] = bSrc[(size_t)(kk + j) * 2048];                 \
    if (tid < 128) {                                             \
      g0##SUF = *(const float4*)(gaSrc + kk);                    \
      g1##SUF = *(const float4*)(gaSrc + kk + 4); } }

#define G1_BODY(BUF, SUF, NXT) {                                               \
    *(uint4*)&Ap[BUF][aOff0] = a0##SUF;                                        \
    *(uint4*)&Ap[BUF][aOff1] = a1##SUF;                                        \
    { u16x8 o0, o1;                                                            \
      _Pragma("unroll") for (int j = 0; j < 8; ++j) {                          \
        o0[j] = f2bf(b##SUF[j]); o1[j] = f2bf(b##SUF[j + 8]); }                \
      *(u16x8*)&Bp[BUF][bOff0] = o0;                                           \
      *(u16x8*)&Bp[BUF][bOff1] = o1; }                                         \
    if (tid < 128) { u16x8 og;                                                 \
      og[0]=f2bf(g0##SUF.x); og[1]=f2bf(g0##SUF.y);                            \
      og[2]=f2bf(g0##SUF.z); og[3]=f2bf(g0##SUF.w);                            \
      og[4]=f2bf(g1##SUF.x); og[5]=f2bf(g1##SUF.y);                            \
      og[6]=f2bf(g1##SUF.z); og[7]=f2bf(g1##SUF.w);                            \
      *(u16x8*)&Bp2[BUF][gaOff] = og; }                                        \
    PIPE_BARRIER();                                                            \
    if ((NXT) < 32) G1_LOAD(SUF, NXT);                                         \
    _Pragma("unroll") for (int ks = 0; ks < 64; ks += 32) {                    \
      int kb = ks + lh * 8;                                                    \
      s16x8 af[2], bg[2], bu[2], bt;                                           \
      _Pragma("unroll") for (int q = 0; q < 2; ++q) {                          \
        int ar = wr * 32 + q * 16 + lr;                                        \
        af[q] = *(const s16x8*)&Ap[BUF][ar * 64 + (kb ^ ((ar & 7) << 3))];     \
      }                                                                        \
      _Pragma("unroll") for (int r = 0; r < 2; ++r) {                          \
        int bc = ni * 32 + r * 16 + lr;                                        \
        bg[r] = *(const s16x8*)&Bp[BUF][bc * 64 + (kb ^ ((bc & 7) << 3))];     \
        bu[r] = *(const s16x8*)&Bp[BUF][(bc + 64) * 64 + (kb ^ ((bc & 7) << 3))]; \
      }                                                                        \
      bt = *(const s16x8*)&Bp2[BUF][lr * 64 + (kb ^ ((lr & 7) << 3))];         \
      _Pragma("unroll") for (int q = 0; q < 2; ++q) {                          \
        _Pragma("unroll") for (int r = 0; r < 2; ++r) {                        \
          accg[q][r] = __builtin_amdgcn_mfma_f32_16x16x32_bf16(af[q], bg[r], accg[q][r], 0, 0, 0); \
          accu[q][r] = __builtin_amdgcn_mfma_f32_16x16x32_bf16(af[q], bu[r], accu[q][r], 0, 0, 0); \
        }                                                                      \
        acct1[q] = __builtin_amdgcn_mfma_f32_16x16x32_bf16(af[q], bt, acct1[q], 0, 0, 0); \
      }                                                                        \
    } }

  f32x4 accg[2][2] = {}, accu[2][2] = {};
  f32x4 acct1[2] = {};
  G1_LOAD(A, 0);
  G1_LOAD(B, 1);
  G1_LOAD(C, 2);
  for (int tt = 0; tt < 30; tt += 6) {
    G1_BODY(0, A, tt + 3);
    G1_BODY(1, B, tt + 4);
    G1_BODY(0, C, tt + 5);
    G1_BODY(1, A, tt + 6);
    G1_BODY(0, B, tt + 7);
    G1_BODY(1, C, tt + 8);
  }
  G1_BODY(0, A, 99);   // tile 30
  G1_BODY(1, B, 99);   // tile 31
#undef G1_LOAD
#undef G1_BODY

  // ---- epilogue: dump in-register ter1 to LDS, fuse LoRA + silu, store h ----
  __syncthreads();
  float* tlds = (float*)&Ap[0][0];             // 128 x 16 f32
  if (ni == 0) {
#pragma unroll
    for (int q = 0; q < 2; ++q)
#pragma unroll
      for (int j = 0; j < 4; ++j) {
        int row = wr * 32 + q * 16 + lh * 4 + j;
        tlds[row * 16 + lr] = acct1[q][j];
      }
  }
  __syncthreads();
#pragma unroll
  for (int r = 0; r < 2; ++r) {
    int gc = c0 + ni * 32 + r * 16 + lr;       // global i-col 0..1023
    const float4* g4 = (const float4*)(gupB + ((size_t)e * 2048 + gc) * 16);
    const float4* u4 = (const float4*)(gupB + ((size_t)e * 2048 + 1024 + gc) * 16);
    float gv2[16], uv2[16];
#pragma unroll
    for (int q = 0; q < 4; ++q) {
      float4 gv = g4[q], uv = u4[q];
      gv2[q*4+0]=gv.x; gv2[q*4+1]=gv.y; gv2[q*4+2]=gv.z; gv2[q*4+3]=gv.w;
      uv2[q*4+0]=uv.x; uv2[q*4+1]=uv.y; uv2[q*4+2]=uv.z; uv2[q*4+3]=uv.w;
    }
#pragma unroll
    for (int q = 0; q < 2; ++q) {
#pragma unroll
      for (int j = 0; j < 4; ++j) {
        int row = wr * 32 + q * 16 + lh * 4 + j;
        if (st * 128 + row < n) {
          int p = list[e * 512 + st * 128 + row];
          const float* tv = &tlds[row * 16];
          float dg = 0.f, du = 0.f;
#pragma unroll
          for (int rr = 0; rr < 16; ++rr) { dg += tv[rr] * gv2[rr]; du += tv[rr] * uv2[rr]; }
          float g = accg[q][r][j] + 2.f * dg;
          float u = accu[q][r][j] + 2.f * du;
          h[(size_t)p * 1024 + gc] = f2bf(g / (1.f + __expf(-g)) * u);
        }
      }
    }
  }
}

// ---------------------------------------------------------------------------
// GEMM2: gathered h rows [BM=128] x down[e] [BN=64], full K=1024 (NT=16),
// 3-deep pipeline. FUSED: ter2 = h . dlA[e] as +2 MFMA/body (Bp2 tile).
// Epilogue fuses down-LoRA + routing weight; atomicAdd into zeroed y.
__global__ __launch_bounds__(512) void k_gemm2(
    const unsigned short* __restrict__ h, const float* __restrict__ down,
    const float* __restrict__ dlA, const float* __restrict__ dlB,
    const int* __restrict__ cnt, const int* __restrict__ list,
    const float* __restrict__ pw, float* __restrict__ y) {
  const int id = blockIdx.x;                 // 0..1023
  const int e  = id & 7;
  const int m  = id >> 3;
  const int ct = m & 31;                     // 0..31
  const int st = m >> 5;                     // 0..3
  const int n = cnt[e];
  if (st * 128 >= n) return;
  const int tid = threadIdx.x;

  __shared__ unsigned short Ap[2][128 * 64];
  __shared__ unsigned short Bp[2][64 * 64];
  __shared__ unsigned short Bp2[2][16 * 64];   // dlA [r][k]

  const int c0 = ct * 64;

  const unsigned short *aSrc0, *aSrc1;
  int aOff0, aOff1;
  {
    int row = tid >> 3, k16 = tid & 7;
    int p = list[e * 512 + min(st * 128 + row, n - 1)];
    aSrc0 = h + (size_t)p * 1024 + k16 * 8;
    aOff0 = row * 64 + ((k16 * 8) ^ ((row & 7) << 3));
    int slot = tid + 512;
    row = slot >> 3; k16 = slot & 7;
    p = list[e * 512 + min(st * 128 + row, n - 1)];
    aSrc1 = h + (size_t)p * 1024 + k16 * 8;
    aOff1 = row * 64 + ((k16 * 8) ^ ((row & 7) << 3));
  }
  const int bcol = tid & 63, kg = tid >> 6;  // 8 k-groups of 8
  const float* bSrc = down + (size_t)e * 1024 * 2048 + (size_t)(kg * 8) * 2048 + c0 + bcol;
  const int bOff = bcol * 64 + ((kg * 8) ^ ((bcol & 7) << 3));

  // dlA sub-tile staging (threads 0..127): 16 r x 8 k-chunks
  const int gr = (tid >> 3) & 15, gk = tid & 7;
  const float* gaSrc = dlA + ((size_t)e * 16 + gr) * 1024 + gk * 8;
  const int gaOff = gr * 64 + ((gk * 8) ^ ((gr & 7) << 3));

  const int lane = tid & 63, wv = tid >> 6;
  const int lr = lane & 15, lh = lane >> 4;
  const int wr = wv >> 1, ni = wv & 1;

  uint4 a0A, a1A, a0B, a1B, a0C, a1C;
  float bA[8], bB[8], bC[8];
  float4 g0A, g1A, g0B, g1B, g0C, g1C;

#define G2_LOAD(SUF, T) {                                        \
    const int kk = (T) * 64;                                     \
    a0##SUF = *(const uint4*)(aSrc0 + kk);                       \
    a1##SUF = *(const uint4*)(aSrc1 + kk);                       \
    _Pragma("unroll") for (int j = 0; j < 8; ++j)                \
      b##SUF[j] = bSrc[(size_t)(kk + j) * 2048];                 \
    if (tid < 128) {                                             \
      g0##SUF = *(const float4*)(gaSrc + kk);                    \
      g1##SUF = *(const float4*)(gaSrc + kk + 4); } }

#define G2_BODY(BUF, SUF, NXT) {                                               \
    *(uint4*)&Ap[BUF][aOff0] = a0##SUF;                                        \
    *(uint4*)&Ap[BUF][aOff1] = a1##SUF;                                        \
    { u16x8 o;                                                                 \
      _Pragma("unroll") for (int j = 0; j < 8; ++j) o[j] = f2bf(b##SUF[j]);    \
      *(u16x8*)&Bp[BUF][bOff] = o; }                                           \
    if (tid < 128) { u16x8 og;                                                 \
      og[0]=f2bf(g0##SUF.x); og[1]=f2bf(g0##SUF.y);                            \
      og[2]=f2bf(g0##SUF.z); og[3]=f2bf(g0##SUF.w);                            \
      og[4]=f2bf(g1##SUF.x); og[5]=f2bf(g1##SUF.y);                            \
      og[6]=f2bf(g1##SUF.z); og[7]=f2bf(g1##SUF.w);                            \
      *(u16x8*)&Bp2[BUF][gaOff] = og; }                                        \
    PIPE_BARRIER();                                                            \
    if ((NXT) < 16) G2_LOAD(SUF, NXT);                                         \
    _Pragma("unroll") for (int ks = 0; ks < 64; ks += 32) {                    \
      int kb = ks + lh * 8;                                                    \
      s16x8 af[2], bd[2], bt;                                                  \
      _Pragma("unroll") for (int q = 0; q < 2; ++q) {                          \
        int ar = wr * 32 + q * 16 + lr;                                        \
        af[q] = *(const s16x8*)&Ap[BUF][ar * 64 + (kb ^ ((ar & 7) << 3))];     \
      }                                                                        \
      _Pragma("unroll") for (int r = 0; r < 2; ++r) {                          \
        int bc = ni * 32 + r * 16 + lr;                                        \
        bd[r] = *(const s16x8*)&Bp[BUF][bc * 64 + (kb ^ ((bc & 7) << 3))];     \
      }                                                                        \
      bt = *(const s16x8*)&Bp2[BUF][lr * 64 + (kb ^ ((lr & 7) << 3))];         \
      _Pragma("unroll") for (int q = 0; q < 2; ++q) {                          \
        _Pragma("unroll") for (int r = 0; r < 2; ++r)                          \
          acc[q][r] = __builtin_amdgcn_mfma_f32_16x16x32_bf16(af[q], bd[r], acc[q][r], 0, 0, 0); \
        acct2[q] = __builtin_amdgcn_mfma_f32_16x16x32_bf16(af[q], bt, acct2[q], 0, 0, 0); \
      }                                                                        \
    } }

  f32x4 acc[2][2] = {};
  f32x4 acct2[2] = {};
  G2_LOAD(A, 0);
  G2_LOAD(B, 1);
  G2_LOAD(C, 2);
  for (int tt = 0; tt < 12; tt += 6) {
    G2_BODY(0, A, tt + 3);
    G2_BODY(1, B, tt + 4);
    G2_BODY(0, C, tt + 5);
    G2_BODY(1, A, tt + 6);
    G2_BODY(0, B, tt + 7);
    G2_BODY(1, C, tt + 8);
  }
  G2_BODY(0, A, 15);   // tile 12, loads tile 15 into set A
  G2_BODY(1, B, 99);   // tile 13
  G2_BODY(0, C, 99);   // tile 14
  G2_BODY(1, A, 99);   // tile 15
#undef G2_LOAD
#undef G2_BODY

  // ---- epilogue: dump ter2 to LDS, fuse down-LoRA + weight, add into y ----
  __syncthreads();
  float* t2l = (float*)&Ap[0][0];            // 128 x 16 f32
  if (ni == 0) {
#pragma unroll
    for (int q = 0; q < 2; ++q)
#pragma unroll
      for (int j = 0; j < 4; ++j) {
        int row = wr * 32 + q * 16 + lh * 4 + j;
        t2l[row * 16 + lr] = acct2[q][j];
      }
  }
  __syncthreads();
#pragma unroll
  for (int r = 0; r < 2; ++r) {
    int yc = c0 + ni * 32 + r * 16 + lr;
    const float4* d4 = (const float4*)(dlB + ((size_t)e * 2048 + yc) * 16);
    float d2[16];
#pragma unroll
    for (int q = 0; q < 4; ++q) {
      float4 v = d4[q];
      d2[q*4+0]=v.x; d2[q*4+1]=v.y; d2[q*4+2]=v.z; d2[q*4+3]=v.w;
    }
#pragma unroll
    for (int q = 0; q < 2; ++q) {
#pragma unroll
      for (int j = 0; j < 4; ++j) {
        int row = wr * 32 + q * 16 + lh * 4 + j;
        if (st * 128 + row < n) {
          int p = list[e * 512 + st * 128 + row];
          const float* tv = &t2l[row * 16];
          float dd = 0.f;
#pragma unroll
          for (int rr = 0; rr < 16; ++rr) dd += tv[rr] * d2[rr];
          atomicAdd(&y[(size_t)(p >> 1) * 2048 + yc],
                    pw[p] * (acc[q][r][j] + 2.f * dd));
        }
      }
    }
  }
}

// ---------------------------------------------------------------------------
extern "C" void kernel_launch(void* const* d_in, const int* in_sizes, int n_in,
                              void* d_out, int out_size, void* d_ws, size_t ws_size,
                              hipStream_t stream) {
  (void)in_sizes; (void)n_in; (void)ws_size;
  const float* x    = (const float*)d_in[0];
  const float* gw   = (const float*)d_in[1];
  const float* gA   = (const float*)d_in[2];
  const float* gB   = (const float*)d_in[3];
  const float* gup  = (const float*)d_in[4];
  const float* down = (const float*)d_in[5];
  const float* gupA = (const float*)d_in[6];
  const float* gupB = (const float*)d_in[7];
  const float* dlA  = (const float*)d_in[8];
  const float* dlB  = (const float*)d_in[9];
  float* y = (float*)d_out;

  char* w = (char*)d_ws;
  int*   cnt           = (int*)(w + OFF_CNT);
  int*   list          = (int*)(w + OFF_LIST);
  float* pw            = (float*)(w + OFF_PW);
  float* Wg            = (float*)(w + OFF_WG);
  unsigned short* xbf  = (unsigned short*)(w + OFF_XBF);
  unsigned short* hbuf = (unsigned short*)(w + OFF_H);

  hipMemsetAsync(w, 0, ZERO_SPAN, stream);
  hipMemsetAsync(y, 0, (size_t)out_size * sizeof(float), stream);

  k_gatecomb<<<64, 256, 0, stream>>>(gw, gA, gB, Wg);
  k_router<<<512, 256, 0, stream>>>(x, Wg, cnt, list, pw, xbf);
  k_gemm1<<<512, 512, 0, stream>>>(xbf, gup, gupA, gupB, cnt, list, hbuf);
  k_gemm2<<<1024, 512, 0, stream>>>(hbuf, down, dlA, dlB, cnt, list, pw, y);
}